// Round 5
// baseline (2812.964 us; speedup 1.0000x reference)
//
#include <hip/hip_runtime.h>

typedef _Float16 f16;
typedef _Float16 f16x4 __attribute__((ext_vector_type(4)));
typedef _Float16 f16x8 __attribute__((ext_vector_type(8)));
typedef float    f32x4 __attribute__((ext_vector_type(4)));

static constexpr int NTOK = 8192;
static constexpr int DIN  = 4096;
static constexpr int DOUT = 4096;
static constexpr int NE   = 8;
static constexpr int RNK  = 512;
static constexpr float LOSC  = 2048.0f;   // lo terms stored pre-scaled by 2^11 (fp16 denormal dodge)
static constexpr float ILOSC = 1.0f/2048.0f;

#define AS1 __attribute__((address_space(1)))
#define AS3 __attribute__((address_space(3)))

// ---------------------------------------------------------------------------
// split hidden_states into fp16 hi/lo and compute ||x||^2 per row (double)
// ---------------------------------------------------------------------------
__global__ __launch_bounds__(256) void split_x_k(const float* __restrict__ X,
    f16* __restrict__ Xhi, f16* __restrict__ Xlo, double* __restrict__ normx)
{
    const int row = blockIdx.x, tid = threadIdx.x;
    const float4* xr = (const float4*)(X + (size_t)row * DIN);
    f16x4* hr = (f16x4*)(Xhi + (size_t)row * DIN);
    f16x4* lr = (f16x4*)(Xlo + (size_t)row * DIN);
    double acc = 0.0;
    #pragma unroll
    for (int it = 0; it < 4; ++it) {
        int i = tid + it * 256;
        float4 v = xr[i];
        float vv[4] = {v.x, v.y, v.z, v.w};
        f16x4 h, l;
        #pragma unroll
        for (int j = 0; j < 4; ++j) {
            f16 hh = (f16)vv[j];
            h[j] = hh;
            l[j] = (f16)((vv[j] - (float)hh) * LOSC);
            acc += (double)vv[j] * (double)vv[j];
        }
        hr[i] = h; lr[i] = l;
    }
    #pragma unroll
    for (int m = 1; m < 64; m <<= 1) acc += __shfl_xor(acc, m, 64);
    __shared__ double sred[4];
    if ((tid & 63) == 0) sred[tid >> 6] = acc;
    __syncthreads();
    if (tid == 0) normx[row] = sred[0] + sred[1] + sred[2] + sred[3];
}

// ---------------------------------------------------------------------------
// transpose gate_weight [E][D][R] fp32 -> GT [E][R][D] fp16 hi/lo (row-major, K contiguous)
// ---------------------------------------------------------------------------
__global__ __launch_bounds__(256) void trans_gate_k(const float* __restrict__ GW,
    f16* __restrict__ GThi, f16* __restrict__ GTlo)
{
    __shared__ float t[64][65];
    const int e = blockIdx.z;
    const int r0 = blockIdx.x * 64, d0 = blockIdx.y * 64;
    const float* src = GW + (size_t)e * DIN * RNK;
    const int c = threadIdx.x & 63, rq = threadIdx.x >> 6;
    #pragma unroll
    for (int i = 0; i < 16; ++i) {
        int dr = i * 4 + rq;
        t[dr][c] = src[(size_t)(d0 + dr) * RNK + r0 + c];
    }
    __syncthreads();
    const size_t obase = (size_t)e * RNK * DIN;
    #pragma unroll
    for (int i = 0; i < 16; ++i) {
        int rr = i * 4 + rq;
        float v = t[c][rr];
        f16 h = (f16)v;
        size_t idx = obase + (size_t)(r0 + rr) * DIN + d0 + c;
        GThi[idx] = h;
        GTlo[idx] = (f16)((v - (float)h) * LOSC);
    }
}

// ---------------------------------------------------------------------------
// fp32 -> fp16 elementwise convert (weights; single precision level is enough)
// ---------------------------------------------------------------------------
__global__ __launch_bounds__(256) void conv16_k(const float* __restrict__ src,
    f16* __restrict__ dst, long n4)
{
    long i = (long)blockIdx.x * 256 + threadIdx.x;
    const long stride = (long)gridDim.x * 256;
    for (; i < n4; i += stride) {
        float4 v = ((const float4*)src)[i];
        f16x4 h = { (f16)v.x, (f16)v.y, (f16)v.z, (f16)v.w };
        ((f16x4*)dst)[i] = h;
    }
}

// ---------------------------------------------------------------------------
// Split-precision 128x128 MFMA GEMM, K-half phase pipeline (counted vmcnt):
// each K-tile (64) = 2 phases of K=32; per phase: vmcnt(8); s_barrier;
// stage next tile's same K-half (8 gload_lds); ds_read + 48 MFMA.
// LDS: [2 dbuf][4 op: Ah,Bh,Al,Bl][2 kh][128][32] f16 = 128 KiB.
// KIND 0: G = V^T V      (M=N=512, K=4096, z=expert) -> Ghi/Glo
// KIND 1: T = X Vt^T     (M=8192, N=4096, K=4096) -> Thi/Tlo + rowpT; XCD swizzle
// KIND 2: s2 = sum((TG) o T) (M=8192, N=512 per e, K=512, z=expert) -> rowpU
// ---------------------------------------------------------------------------
template<int KIND>
__global__ __launch_bounds__(256, 1) void gemm_k(
    const f16* __restrict__ Ah, const f16* __restrict__ Al,
    const f16* __restrict__ Bh, const f16* __restrict__ Bl,
    f16* __restrict__ Chi, f16* __restrict__ Clo,
    float* __restrict__ rowp,
    const f16* __restrict__ Th, const f16* __restrict__ Tl)
{
    constexpr int KDIM = (KIND == 2) ? 512 : 4096;
    constexpr int LDB  = (KIND == 2) ? 512 : 4096;
    constexpr int NT   = KDIM / 64;

    int bm, bn, z;
    if constexpr (KIND == 1) {
        // bijective XCD swizzle: 2048 blocks, 8 XCDs, 256/chunk; bm-innermost
        const int orig = blockIdx.x;
        const int wg = (orig & 7) * 256 + (orig >> 3);
        bm = wg & 63; bn = wg >> 6; z = 0;
    } else {
        bm = blockIdx.x; bn = blockIdx.y; z = blockIdx.z;
    }
    const int tid = threadIdx.x;
    const int lane = tid & 63, wv = tid >> 6;
    const int wr = wv >> 1, wc = wv & 1;
    const int m0 = bm * 128, n0 = bn * 128;

    __shared__ f16 smem[65536]; // [2 buf][Ah,Bh,Al,Bl][2 kh][128][32]

    long aBase = 0, bBase = 0;
    if constexpr (KIND == 0) { aBase = (long)z * RNK * DIN; bBase = aBase; }
    if constexpr (KIND == 2) { aBase = (long)z * RNK; bBase = (long)z * RNK * RNK; }

    // per-thread staging sources (pre-swizzled global col): g=j*256+tid, r=g>>2, u=g&3
    long s2A[2], s2B[2];
    #pragma unroll
    for (int j = 0; j < 2; ++j) {
        int g = j * 256 + tid;
        int r = g >> 2, u = g & 3;
        int sc = (u ^ ((r >> 1) & 3)) * 8;
        s2A[j] = aBase + (long)(m0 + r) * DIN + sc;
        s2B[j] = bBase + (long)(n0 + r) * LDB + sc;
    }

    auto stage_op = [&](int dstE, const f16* __restrict__ src, const long* s2, int kOff) {
        #pragma unroll
        for (int j = 0; j < 2; ++j) {
            int g = j * 256 + tid;
            __builtin_amdgcn_global_load_lds(
                (const AS1 void*)(src + s2[j] + kOff),
                (AS3 void*)(&smem[dstE + g * 8]), 16, 0, 0);
        }
    };
    auto stage_all = [&](int buf, int kh, int kOff) {
        const int e0 = buf * 32768 + kh * 4096;
        stage_op(e0,         Ah, s2A, kOff);
        stage_op(e0 + 8192,  Bh, s2B, kOff);
        stage_op(e0 + 16384, Al, s2A, kOff);
        stage_op(e0 + 24576, Bl, s2B, kOff);
    };

    f32x4 acc[4][4], accB_[4][4];
    #pragma unroll
    for (int a = 0; a < 4; ++a)
        #pragma unroll
        for (int b = 0; b < 4; ++b) {
            acc[a][b]   = f32x4{0.f, 0.f, 0.f, 0.f};
            accB_[a][b] = f32x4{0.f, 0.f, 0.f, 0.f};
        }

    const int q = lane >> 4, li = lane & 15;

    // prologue: both K-halves of tile 0
    stage_all(0, 0, 0);
    stage_all(0, 1, 32);

    for (int t = 0; t < NT; ++t) {
        const int buf = t & 1;
        const int ts = (t + 1 < NT) ? t + 1 : t;   // tail: dead re-stage keeps vmcnt uniform
        #pragma unroll
        for (int kh = 0; kh < 2; ++kh) {
            asm volatile("s_waitcnt vmcnt(8)" ::: "memory"); // land stages from 2 phases ago
            __builtin_amdgcn_s_barrier();                    // make it global
            __builtin_amdgcn_sched_barrier(0);               // no reads cross upward
            stage_all(buf ^ 1, kh, ts * 64 + kh * 32);
            const char* base = (const char*)smem + buf * 65536 + kh * 8192;
            f16x8 bhf[4], blf[4];
            #pragma unroll
            for (int fn = 0; fn < 4; ++fn) {
                int rb = wc * 64 + fn * 16 + li;
                int off = rb * 64 + ((q ^ ((rb >> 1) & 3)) << 4);
                bhf[fn] = *(const f16x8*)(base + 16384 + off);
                blf[fn] = *(const f16x8*)(base + 49152 + off);
            }
            __builtin_amdgcn_s_setprio(1);
            #pragma unroll
            for (int fm = 0; fm < 4; ++fm) {
                int ra = wr * 64 + fm * 16 + li;
                int offA = ra * 64 + ((q ^ ((ra >> 1) & 3)) << 4);
                f16x8 ahf = *(const f16x8*)(base + offA);
                f16x8 alv = *(const f16x8*)(base + 32768 + offA);
                #pragma unroll
                for (int fn = 0; fn < 4; ++fn) {
                    acc[fm][fn]   = __builtin_amdgcn_mfma_f32_16x16x32_f16(ahf, bhf[fn], acc[fm][fn],   0, 0, 0);
                    accB_[fm][fn] = __builtin_amdgcn_mfma_f32_16x16x32_f16(ahf, blf[fn], accB_[fm][fn], 0, 0, 0);
                    accB_[fm][fn] = __builtin_amdgcn_mfma_f32_16x16x32_f16(alv, bhf[fn], accB_[fm][fn], 0, 0, 0);
                }
            }
            __builtin_amdgcn_s_setprio(0);
        }
    }

    const int lr_ = (lane >> 4) * 4;
    const int lc_ = lane & 15;
    const int rB = m0 + wr * 64;
    const int cB = n0 + wc * 64;

    if constexpr (KIND == 0) {
        #pragma unroll
        for (int fm = 0; fm < 4; ++fm)
            #pragma unroll
            for (int fn = 0; fn < 4; ++fn)
                #pragma unroll
                for (int j = 0; j < 4; ++j) {
                    float v = acc[fm][fn][j] + accB_[fm][fn][j] * ILOSC;
                    long row = rB + fm * 16 + lr_ + j;
                    long col = cB + fn * 16 + lc_;
                    long idx = (long)z * RNK * RNK + row * RNK + col;
                    f16 h = (f16)v;
                    Chi[idx] = h;
                    Clo[idx] = (f16)((v - (float)h) * LOSC);
                }
    } else {
        const int e8 = (KIND == 1) ? (((bn >> 2) << 3) + ((bn & 3) << 1) + wc)
                                   : ((z << 3) + (bn << 1) + wc);
        #pragma unroll
        for (int fm = 0; fm < 4; ++fm) {
            float rs[4] = {0.f, 0.f, 0.f, 0.f};
            #pragma unroll
            for (int fn = 0; fn < 4; ++fn)
                #pragma unroll
                for (int j = 0; j < 4; ++j) {
                    float v = acc[fm][fn][j] + accB_[fm][fn][j] * ILOSC;
                    long row = rB + fm * 16 + lr_ + j;
                    long col = cB + fn * 16 + lc_;
                    if constexpr (KIND == 1) {
                        long idx = row * (long)DIN + col;
                        f16 h = (f16)v;
                        Chi[idx] = h;
                        Clo[idx] = (f16)((v - (float)h) * LOSC);
                        rs[j] += v * v;
                    } else {
                        long tidx = row * (long)DIN + (long)z * RNK + col;
                        float tv = (float)Th[tidx] + (float)Tl[tidx] * ILOSC;
                        rs[j] += v * tv;
                    }
                }
            #pragma unroll
            for (int j = 0; j < 4; ++j) {
                float s = rs[j];
                s += __shfl_xor(s, 1, 64);
                s += __shfl_xor(s, 2, 64);
                s += __shfl_xor(s, 4, 64);
                s += __shfl_xor(s, 8, 64);
                if (lc_ == 0) {
                    long row = rB + fm * 16 + lr_ + j;
                    rowp[row * 64 + e8] = s;
                }
            }
        }
    }
}

// ---------------------------------------------------------------------------
// 256x256 MFMA GEMM, K-half phase pipeline (counted vmcnt), 512 thr (2Mx4N waves),
// XCD-bijective-swizzled 1D grid, bm-innermost decode.
// LDS: [2 dbuf][A,B][2 kh][256][32] f16 = 128 KiB. Per phase: vmcnt(4);
// s_barrier; stage 4 gload_lds; 12 ds_read_b128 + 32 MFMA (setprio-wrapped).
// KIND 3: pretrained dense -> fp32 out + bias[n]
// KIND 4: expert gather    -> f16 Yg rows via toklist, z = expert, bias[z][n]
// ---------------------------------------------------------------------------
template<int KIND>
__global__ __launch_bounds__(512, 1) void gemm256_k(
    const f16* __restrict__ A, const f16* __restrict__ Bm,
    float* __restrict__ Cf, f16* __restrict__ Ch, const float* __restrict__ bias,
    const int* __restrict__ toklist, const int* __restrict__ cnt, const int* __restrict__ offs,
    int Mtiles, int Ntiles)
{
    // bijective XCD swizzle (m204): each XCD gets a contiguous logical range
    const int nwg = gridDim.x;
    const int orig = blockIdx.x;
    const int qq = nwg >> 3, rr8 = nwg & 7;
    const int xcd = orig & 7, pos = orig >> 3;
    const int wg = (xcd < rr8 ? xcd * (qq + 1) : rr8 * (qq + 1) + (xcd - rr8) * qq) + pos;
    const int bm = wg % Mtiles;
    const int rest = wg / Mtiles;
    const int bn = rest % Ntiles;
    const int z  = rest / Ntiles;

    const int tid = threadIdx.x;
    const int lane = tid & 63, wv = tid >> 6;
    const int wr = wv >> 2, wc = wv & 3;          // 2 x 4 wave grid
    const int m0 = bm * 256, n0 = bn * 256;

    int cntz = 0, offz = 0;
    if constexpr (KIND == 4) {
        cntz = cnt[z]; offz = offs[z];
        if (m0 >= cntz) return;
    }

    __shared__ f16 smem[65536];                   // [2 buf][A,B][2 kh][256][32]

    long bBase = 0;
    if constexpr (KIND == 4) bBase = (long)z * DOUT * DIN;

    // per-thread staging sources: g=j*512+tid, r=g>>2 in [0,256), u=g&3
    long srcA2[2], srcB2[2];
    #pragma unroll
    for (int j = 0; j < 2; ++j) {
        int g = j * 512 + tid;
        int r = g >> 2, u = g & 3;
        int sc = (u ^ ((r >> 1) & 3)) * 8;        // pre-swizzled col (f16 elems)
        if constexpr (KIND == 4) {
            int rg = m0 + r;
            int tok = (rg < cntz) ? toklist[offz + rg] : 0;
            srcA2[j] = (long)tok * DIN + sc;
        } else {
            srcA2[j] = (long)(m0 + r) * DIN + sc;
        }
        srcB2[j] = bBase + (long)(n0 + r) * DIN + sc;
    }

    auto stage2 = [&](int buf, int kh, int kOff) {
        const int e0 = buf * 32768 + kh * 8192;
        #pragma unroll
        for (int j = 0; j < 2; ++j) {
            int g = j * 512 + tid;
            __builtin_amdgcn_global_load_lds(
                (const AS1 void*)(A + srcA2[j] + kOff),
                (AS3 void*)(&smem[e0 + g * 8]), 16, 0, 0);
        }
        #pragma unroll
        for (int j = 0; j < 2; ++j) {
            int g = j * 512 + tid;
            __builtin_amdgcn_global_load_lds(
                (const AS1 void*)(Bm + srcB2[j] + kOff),
                (AS3 void*)(&smem[e0 + 16384 + g * 8]), 16, 0, 0);
        }
    };

    f32x4 acc[8][4];
    #pragma unroll
    for (int a = 0; a < 8; ++a)
        #pragma unroll
        for (int b = 0; b < 4; ++b) acc[a][b] = f32x4{0.f, 0.f, 0.f, 0.f};

    const int q = lane >> 4, li = lane & 15;

    // prologue: both K-halves of tile 0
    stage2(0, 0, 0);
    stage2(0, 1, 32);

    for (int t = 0; t < 64; ++t) {
        const int buf = t & 1;
        const int ts = (t + 1 < 64) ? t + 1 : t;
        #pragma unroll
        for (int kh = 0; kh < 2; ++kh) {
            asm volatile("s_waitcnt vmcnt(4)" ::: "memory"); // land stages from 2 phases ago
            __builtin_amdgcn_s_barrier();
            __builtin_amdgcn_sched_barrier(0);
            stage2(buf ^ 1, kh, ts * 64 + kh * 32);
            const char* base = (const char*)smem + buf * 65536 + kh * 16384;
            f16x8 bhf[4];
            #pragma unroll
            for (int fn = 0; fn < 4; ++fn) {
                int rb = wc * 64 + fn * 16 + li;
                bhf[fn] = *(const f16x8*)(base + 32768 + rb * 64 + ((q ^ ((rb >> 1) & 3)) << 4));
            }
            __builtin_amdgcn_s_setprio(1);
            #pragma unroll
            for (int fm = 0; fm < 8; ++fm) {
                int ra = wr * 128 + fm * 16 + li;
                f16x8 ahf = *(const f16x8*)(base + ra * 64 + ((q ^ ((ra >> 1) & 3)) << 4));
                #pragma unroll
                for (int fn = 0; fn < 4; ++fn)
                    acc[fm][fn] = __builtin_amdgcn_mfma_f32_16x16x32_f16(ahf, bhf[fn], acc[fm][fn], 0, 0, 0);
            }
            __builtin_amdgcn_s_setprio(0);
        }
    }

    const int lr_ = (lane >> 4) * 4;
    const int lc_ = lane & 15;
    #pragma unroll
    for (int fm = 0; fm < 8; ++fm)
        #pragma unroll
        for (int fn = 0; fn < 4; ++fn)
            #pragma unroll
            for (int j = 0; j < 4; ++j) {
                int rloc = wr * 128 + fm * 16 + lr_ + j;
                long col = n0 + wc * 64 + fn * 16 + lc_;
                if constexpr (KIND == 4) {
                    if (m0 + rloc < cntz) {
                        long row = (long)offz + m0 + rloc;
                        Ch[row * (long)DOUT + col] = (f16)(acc[fm][fn][j] + bias[(long)z * DOUT + col]);
                    }
                } else {
                    long row = m0 + rloc;
                    Cf[row * (long)DOUT + col] = acc[fm][fn][j] + bias[col];
                }
            }
}

// ---------------------------------------------------------------------------
// routing: residual^2 = ||x||^2 - 2||t||^2 + tGt ; softmax(-r) ; top-2 & >1/8 mask
// ---------------------------------------------------------------------------
__global__ __launch_bounds__(256) void route_k(const double* __restrict__ normx,
    const float* __restrict__ rowpT, const float* __restrict__ rowpU,
    int* __restrict__ cnt, int* __restrict__ toke, float* __restrict__ tokw)
{
    const int i = blockIdx.x * 256 + threadIdx.x;
    if (i >= NTOK) return;
    const double nx = normx[i];
    double r[NE];
    #pragma unroll
    for (int e = 0; e < NE; ++e) {
        double tn = 0.0, s2 = 0.0;
        #pragma unroll
        for (int s = 0; s < 8; ++s) {
            tn += (double)rowpT[(long)i * 64 + e * 8 + s];
            s2 += (double)rowpU[(long)i * 64 + e * 8 + s];
        }
        double r2 = nx - 2.0 * tn + s2;
        r[e] = sqrt(r2 > 0.0 ? r2 : 0.0);
    }
    double rmin = r[0];
    #pragma unroll
    for (int e = 1; e < NE; ++e) if (r[e] < rmin) rmin = r[e];
    double w[NE], S = 0.0;
    #pragma unroll
    for (int e = 0; e < NE; ++e) { w[e] = exp(rmin - r[e]); S += w[e]; }
    double rw[NE];
    #pragma unroll
    for (int e = 0; e < NE; ++e) rw[e] = w[e] / S;
    // top-2, first-occurrence tie-break (matches lax.top_k)
    int i1 = 0;
    #pragma unroll
    for (int e = 1; e < NE; ++e) if (rw[e] > rw[i1]) i1 = e;
    int i2 = (i1 == 0) ? 1 : 0;
    #pragma unroll
    for (int e = 0; e < NE; ++e) if (e != i2 && e != i1 && rw[e] > rw[i2]) i2 = e;
    double f1 = (rw[i1] > 0.125) ? rw[i1] : 0.0;
    double f2 = (rw[i2] > 0.125) ? rw[i2] : 0.0;
    double s = f1 + f2;
    int e0 = -1, e1 = -1; float w0 = 0.f, w1 = 0.f;
    if (s > 0.0) {
        if (f1 > 0.0) { e0 = i1; w0 = (float)(f1 / s); }
        if (f2 > 0.0) { e1 = i2; w1 = (float)(f2 / s); }
    }
    toke[i * 2 + 0] = e0; toke[i * 2 + 1] = e1;
    tokw[i * 2 + 0] = w0; tokw[i * 2 + 1] = w1;
    if (e0 >= 0) atomicAdd(&cnt[e0], 1);
    if (e1 >= 0) atomicAdd(&cnt[e1], 1);
}

__global__ void offs_k(const int* __restrict__ cnt, int* __restrict__ offs)
{
    if (threadIdx.x == 0) {
        int a = 0;
        for (int e = 0; e < NE; ++e) { offs[e] = a; a += cnt[e]; }
    }
}

__global__ __launch_bounds__(256) void assign_k(const int* __restrict__ toke,
    const int* __restrict__ offs, int* __restrict__ cur,
    int* __restrict__ toklist, int* __restrict__ tokslot)
{
    const int i = blockIdx.x * 256 + threadIdx.x;
    if (i >= NTOK) return;
    #pragma unroll
    for (int j = 0; j < 2; ++j) {
        int e = toke[i * 2 + j];
        if (e >= 0) {
            int p = atomicAdd(&cur[e], 1);
            int sl = offs[e] + p;
            toklist[sl] = i;
            tokslot[i * 2 + j] = sl;
        } else {
            tokslot[i * 2 + j] = -1;
        }
    }
}

__global__ __launch_bounds__(256) void combine_k(float* __restrict__ out,
    const f16* __restrict__ Yg, const int* __restrict__ tokslot, const float* __restrict__ tokw)
{
    const int i = blockIdx.x;
    int s0 = tokslot[i * 2 + 0], s1 = tokslot[i * 2 + 1];
    float w0 = (s0 >= 0) ? tokw[i * 2 + 0] : 0.f;
    float w1 = (s1 >= 0) ? tokw[i * 2 + 1] : 0.f;
    const f16x4* y0 = (const f16x4*)(Yg + (size_t)(s0 < 0 ? 0 : s0) * DOUT);
    const f16x4* y1 = (const f16x4*)(Yg + (size_t)(s1 < 0 ? 0 : s1) * DOUT);
    float4* o = (float4*)(out + (size_t)i * DOUT);
    for (int c = threadIdx.x; c < DOUT / 4; c += 256) {
        float4 v = o[c];
        f16x4 a = y0[c], b = y1[c];
        v.x += w0 * (float)a[0] + w1 * (float)b[0];
        v.y += w0 * (float)a[1] + w1 * (float)b[1];
        v.z += w0 * (float)a[2] + w1 * (float)b[2];
        v.w += w0 * (float)a[3] + w1 * (float)b[3];
        o[c] = v;
    }
}

// ---------------------------------------------------------------------------
extern "C" void kernel_launch(void* const* d_in, const int* in_sizes, int n_in,
                              void* d_out, int out_size, void* d_ws, size_t ws_size,
                              hipStream_t stream)
{
    const float* X  = (const float*)d_in[0];
    const float* GW = (const float*)d_in[1];
    const float* Wp = (const float*)d_in[2];
    const float* bp = (const float*)d_in[3];
    const float* We = (const float*)d_in[4];
    const float* be = (const float*)d_in[5];
    float* out = (float*)d_out;

    char* ws = (char*)d_ws;
    size_t o = 0;
    auto alloc = [&](size_t bytes) { char* p = ws + o; o += (bytes + 255) & ~(size_t)255; return p; };

    f16* Xhi = (f16*)alloc((size_t)NTOK * DIN * 2);
    const size_t aliasOff = o;                      // Yg aliases [Xlo..Tlo] (all dead by expert GEMM)
    f16* Xlo  = (f16*)alloc((size_t)NTOK * DIN * 2);
    f16* GThi = (f16*)alloc((size_t)NE * RNK * DIN * 2);
    f16* GTlo = (f16*)alloc((size_t)NE * RNK * DIN * 2);
    f16* Thi  = (f16*)alloc((size_t)NTOK * DIN * 2);
    f16* Tlo  = (f16*)alloc((size_t)NTOK * DIN * 2);
    f16* Yg = (f16*)(ws + aliasOff);                // 2*NTOK x DOUT f16 = 134 MB (fits alias span)
    f16* Wp16 = (f16*)alloc((size_t)DOUT * DIN * 2);
    f16* We16 = (f16*)alloc((size_t)NE * DOUT * DIN * 2);
    f16* Ghi  = (f16*)alloc((size_t)NE * RNK * RNK * 2);
    f16* Glo  = (f16*)alloc((size_t)NE * RNK * RNK * 2);
    double* normx = (double*)alloc((size_t)NTOK * 8);
    float* rowpT  = (float*)alloc((size_t)NTOK * 64 * 4);
    float* rowpU  = (float*)alloc((size_t)NTOK * 64 * 4);
    float* tokw   = (float*)alloc((size_t)NTOK * 2 * 4);
    int* toke     = (int*)alloc((size_t)NTOK * 2 * 4);
    int* tokslot  = (int*)alloc((size_t)NTOK * 2 * 4);
    int* toklist  = (int*)alloc((size_t)2 * NTOK * 4);
    int* cnt      = (int*)alloc(64 * 4);
    int* offs = cnt + 8;
    int* cur  = cnt + 16;

    if (ws_size < o) return; // ws too small -> output stays zero (visible failure)

    hipMemsetAsync(cnt, 0, 64 * 4, stream);

    split_x_k<<<NTOK, 256, 0, stream>>>(X, Xhi, Xlo, normx);
    trans_gate_k<<<dim3(RNK / 64, DIN / 64, NE), 256, 0, stream>>>(GW, GThi, GTlo);
    conv16_k<<<2048, 256, 0, stream>>>(Wp, Wp16, (long)DOUT * DIN / 4);
    conv16_k<<<4096, 256, 0, stream>>>(We, We16, (long)NE * DOUT * DIN / 4);

    // G = V^T V (split precision)
    gemm_k<0><<<dim3(4, 4, NE), 256, 0, stream>>>(GThi, GTlo, GThi, GTlo,
        Ghi, Glo, nullptr, nullptr, nullptr);
    // T = X V (split) + ||t||^2 partials  (1-D XCD-swizzled grid)
    gemm_k<1><<<2048, 256, 0, stream>>>(Xhi, Xlo, GThi, GTlo,
        Thi, Tlo, rowpT, nullptr, nullptr);
    // s2 = t G t^T partials (split)
    gemm_k<2><<<dim3(64, 4, NE), 256, 0, stream>>>(Thi, Tlo, Ghi, Glo,
        nullptr, nullptr, rowpU, Thi, Tlo);

    route_k<<<NTOK / 256, 256, 0, stream>>>(normx, rowpT, rowpU, cnt, toke, tokw);
    offs_k<<<1, 1, 0, stream>>>(cnt, offs);
    assign_k<<<NTOK / 256, 256, 0, stream>>>(toke, offs, cur, toklist, tokslot);

    // pretrained: out = X Wp^T + bp   (256^2 tile, XCD-swizzled, phase pipeline)
    gemm256_k<3><<<32 * 16, 512, 0, stream>>>(Xhi, Wp16,
        out, nullptr, bp, nullptr, nullptr, nullptr, 32, 16);
    // experts (gathered rows): Yg[slot] = f16(X[tok] We^T + be)
    gemm256_k<4><<<NE * 32 * 16, 512, 0, stream>>>(Xhi, We16,
        nullptr, Yg, be, toklist, cnt, offs, 32, 16);

    combine_k<<<NTOK, 256, 0, stream>>>(out, Yg, tokslot, tokw);
}

// Round 6
// 2714.713 us; speedup vs baseline: 1.0362x; 1.0362x over previous
//
#include <hip/hip_runtime.h>

typedef _Float16 f16;
typedef _Float16 f16x4 __attribute__((ext_vector_type(4)));
typedef _Float16 f16x8 __attribute__((ext_vector_type(8)));
typedef float    f32x4 __attribute__((ext_vector_type(4)));

static constexpr int NTOK = 8192;
static constexpr int DIN  = 4096;
static constexpr int DOUT = 4096;
static constexpr int NE   = 8;
static constexpr int RNK  = 512;
static constexpr float LOSC  = 2048.0f;   // lo terms stored pre-scaled by 2^11 (fp16 denormal dodge)
static constexpr float ILOSC = 1.0f/2048.0f;

#define AS1 __attribute__((address_space(1)))
#define AS3 __attribute__((address_space(3)))

// ---------------------------------------------------------------------------
// split hidden_states into fp16 hi/lo and compute ||x||^2 per row (double)
// ---------------------------------------------------------------------------
__global__ __launch_bounds__(256) void split_x_k(const float* __restrict__ X,
    f16* __restrict__ Xhi, f16* __restrict__ Xlo, double* __restrict__ normx)
{
    const int row = blockIdx.x, tid = threadIdx.x;
    const float4* xr = (const float4*)(X + (size_t)row * DIN);
    f16x4* hr = (f16x4*)(Xhi + (size_t)row * DIN);
    f16x4* lr = (f16x4*)(Xlo + (size_t)row * DIN);
    double acc = 0.0;
    #pragma unroll
    for (int it = 0; it < 4; ++it) {
        int i = tid + it * 256;
        float4 v = xr[i];
        float vv[4] = {v.x, v.y, v.z, v.w};
        f16x4 h, l;
        #pragma unroll
        for (int j = 0; j < 4; ++j) {
            f16 hh = (f16)vv[j];
            h[j] = hh;
            l[j] = (f16)((vv[j] - (float)hh) * LOSC);
            acc += (double)vv[j] * (double)vv[j];
        }
        hr[i] = h; lr[i] = l;
    }
    #pragma unroll
    for (int m = 1; m < 64; m <<= 1) acc += __shfl_xor(acc, m, 64);
    __shared__ double sred[4];
    if ((tid & 63) == 0) sred[tid >> 6] = acc;
    __syncthreads();
    if (tid == 0) normx[row] = sred[0] + sred[1] + sred[2] + sred[3];
}

// ---------------------------------------------------------------------------
// transpose gate_weight [E][D][R] fp32 -> GT [E][R][D] fp16 hi/lo (row-major, K contiguous)
// ---------------------------------------------------------------------------
__global__ __launch_bounds__(256) void trans_gate_k(const float* __restrict__ GW,
    f16* __restrict__ GThi, f16* __restrict__ GTlo)
{
    __shared__ float t[64][65];
    const int e = blockIdx.z;
    const int r0 = blockIdx.x * 64, d0 = blockIdx.y * 64;
    const float* src = GW + (size_t)e * DIN * RNK;
    const int c = threadIdx.x & 63, rq = threadIdx.x >> 6;
    #pragma unroll
    for (int i = 0; i < 16; ++i) {
        int dr = i * 4 + rq;
        t[dr][c] = src[(size_t)(d0 + dr) * RNK + r0 + c];
    }
    __syncthreads();
    const size_t obase = (size_t)e * RNK * DIN;
    #pragma unroll
    for (int i = 0; i < 16; ++i) {
        int rr = i * 4 + rq;
        float v = t[c][rr];
        f16 h = (f16)v;
        size_t idx = obase + (size_t)(r0 + rr) * DIN + d0 + c;
        GThi[idx] = h;
        GTlo[idx] = (f16)((v - (float)h) * LOSC);
    }
}

// ---------------------------------------------------------------------------
// fp32 -> fp16 elementwise convert (weights; single precision level is enough)
// ---------------------------------------------------------------------------
__global__ __launch_bounds__(256) void conv16_k(const float* __restrict__ src,
    f16* __restrict__ dst, long n4)
{
    long i = (long)blockIdx.x * 256 + threadIdx.x;
    const long stride = (long)gridDim.x * 256;
    for (; i < n4; i += stride) {
        float4 v = ((const float4*)src)[i];
        f16x4 h = { (f16)v.x, (f16)v.y, (f16)v.z, (f16)v.w };
        ((f16x4*)dst)[i] = h;
    }
}

// ---------------------------------------------------------------------------
// Split-precision 128x128 MFMA GEMM, ring-4 LDS pipeline (BK=32, stage-ahead 3):
// per step: vmcnt(16); s_barrier; sched_barrier; stage tile s+3 (8 gload_lds);
// 16 ds_read_b128 + 48 MFMA. LDS: 4 slots x [Ah|Bh|Al|Bl][128][32] f16 = 128 KiB.
// Rows are 64 B -> fragment reads are 2-way-per-bank (free), NO swizzle anywhere.
// KIND 0: G = V^T V      (M=N=512, K=4096, z=expert) -> Ghi/Glo
// KIND 1: T = X Vt^T     (M=8192, N=4096, K=4096) -> Thi/Tlo + rowpT; XCD swizzle
// KIND 2: s2 = sum((TG) o T) (M=8192, N=512 per e, K=512, z=expert) -> rowpU
// ---------------------------------------------------------------------------
template<int KIND>
__global__ __launch_bounds__(256, 1) void gemm_k(
    const f16* __restrict__ Ah, const f16* __restrict__ Al,
    const f16* __restrict__ Bh, const f16* __restrict__ Bl,
    f16* __restrict__ Chi, f16* __restrict__ Clo,
    float* __restrict__ rowp,
    const f16* __restrict__ Th, const f16* __restrict__ Tl)
{
    constexpr int KDIM = (KIND == 2) ? 512 : 4096;
    constexpr int LDB  = (KIND == 2) ? 512 : 4096;
    constexpr int NT   = KDIM / 32;

    int bm, bn, z;
    if constexpr (KIND == 1) {
        // bijective XCD swizzle: 2048 blocks, 8 XCDs, 256/chunk; bm-innermost
        const int orig = blockIdx.x;
        const int wg = (orig & 7) * 256 + (orig >> 3);
        bm = wg & 63; bn = wg >> 6; z = 0;
    } else {
        bm = blockIdx.x; bn = blockIdx.y; z = blockIdx.z;
    }
    const int tid = threadIdx.x;
    const int lane = tid & 63, wv = tid >> 6;
    const int wr = wv >> 1, wc = wv & 1;
    const int m0 = bm * 128, n0 = bn * 128;

    __shared__ f16 smem[65536]; // 4 slots x 16384 f16: [Ah 0][Bh 4096][Al 8192][Bl 12288]

    long aBase = 0, bBase = 0;
    if constexpr (KIND == 0) { aBase = (long)z * RNK * DIN; bBase = aBase; }
    if constexpr (KIND == 2) { aBase = (long)z * RNK; bBase = (long)z * RNK * RNK; }

    // per-thread staging sources (linear, no swizzle): g=j*256+tid, r=g>>2, u=g&3
    long s2A[2], s2B[2];
    #pragma unroll
    for (int j = 0; j < 2; ++j) {
        int g = j * 256 + tid;
        int r = g >> 2, u = g & 3;
        s2A[j] = aBase + (long)(m0 + r) * DIN + u * 8;
        s2B[j] = bBase + (long)(n0 + r) * LDB + u * 8;
    }

    auto stage = [&](int slot, int kOff) {
        const int e0 = slot * 16384;
        #pragma unroll
        for (int j = 0; j < 2; ++j) {
            int g = j * 256 + tid;
            __builtin_amdgcn_global_load_lds((const AS1 void*)(Ah + s2A[j] + kOff),
                (AS3 void*)(&smem[e0 + g * 8]), 16, 0, 0);
            __builtin_amdgcn_global_load_lds((const AS1 void*)(Bh + s2B[j] + kOff),
                (AS3 void*)(&smem[e0 + 4096 + g * 8]), 16, 0, 0);
            __builtin_amdgcn_global_load_lds((const AS1 void*)(Al + s2A[j] + kOff),
                (AS3 void*)(&smem[e0 + 8192 + g * 8]), 16, 0, 0);
            __builtin_amdgcn_global_load_lds((const AS1 void*)(Bl + s2B[j] + kOff),
                (AS3 void*)(&smem[e0 + 12288 + g * 8]), 16, 0, 0);
        }
    };

    f32x4 acc[4][4], accB_[4][4];
    #pragma unroll
    for (int a = 0; a < 4; ++a)
        #pragma unroll
        for (int b = 0; b < 4; ++b) {
            acc[a][b]   = f32x4{0.f, 0.f, 0.f, 0.f};
            accB_[a][b] = f32x4{0.f, 0.f, 0.f, 0.f};
        }

    const int q = lane >> 4, li = lane & 15;

    // prologue: tiles 0,1,2 in flight (24 loads)
    stage(0, 0);
    stage(1, 32);
    stage(2, 64);

    for (int t = 0; t < NT; t += 4) {
        #pragma unroll
        for (int uu = 0; uu < 4; ++uu) {
            const int s = t + uu;
            const int ts = (s + 3 < NT) ? s + 3 : NT - 1;   // tail: dead re-stage keeps vmcnt uniform
            asm volatile("s_waitcnt vmcnt(16)" ::: "memory"); // tile s landed; s+1,s+2 in flight
            __builtin_amdgcn_s_barrier();                     // landing + prior reads global
            __builtin_amdgcn_sched_barrier(0);
            stage((uu + 3) & 3, ts * 32);
            const char* base = (const char*)smem + uu * 32768;
            f16x8 bhf[4], blf[4];
            #pragma unroll
            for (int fn = 0; fn < 4; ++fn) {
                int rb = wc * 64 + fn * 16 + li;
                int off = rb * 64 + q * 16;
                bhf[fn] = *(const f16x8*)(base + 8192 + off);
                blf[fn] = *(const f16x8*)(base + 24576 + off);
            }
            __builtin_amdgcn_s_setprio(1);
            #pragma unroll
            for (int fm = 0; fm < 4; ++fm) {
                int ra = wr * 64 + fm * 16 + li;
                int offA = ra * 64 + q * 16;
                f16x8 ahf = *(const f16x8*)(base + offA);
                f16x8 alv = *(const f16x8*)(base + 16384 + offA);
                #pragma unroll
                for (int fn = 0; fn < 4; ++fn) {
                    acc[fm][fn]   = __builtin_amdgcn_mfma_f32_16x16x32_f16(ahf, bhf[fn], acc[fm][fn],   0, 0, 0);
                    accB_[fm][fn] = __builtin_amdgcn_mfma_f32_16x16x32_f16(ahf, blf[fn], accB_[fm][fn], 0, 0, 0);
                    accB_[fm][fn] = __builtin_amdgcn_mfma_f32_16x16x32_f16(alv, bhf[fn], accB_[fm][fn], 0, 0, 0);
                }
            }
            __builtin_amdgcn_s_setprio(0);
        }
    }

    const int lr_ = (lane >> 4) * 4;
    const int lc_ = lane & 15;
    const int rB = m0 + wr * 64;
    const int cB = n0 + wc * 64;

    if constexpr (KIND == 0) {
        #pragma unroll
        for (int fm = 0; fm < 4; ++fm)
            #pragma unroll
            for (int fn = 0; fn < 4; ++fn)
                #pragma unroll
                for (int j = 0; j < 4; ++j) {
                    float v = acc[fm][fn][j] + accB_[fm][fn][j] * ILOSC;
                    long row = rB + fm * 16 + lr_ + j;
                    long col = cB + fn * 16 + lc_;
                    long idx = (long)z * RNK * RNK + row * RNK + col;
                    f16 h = (f16)v;
                    Chi[idx] = h;
                    Clo[idx] = (f16)((v - (float)h) * LOSC);
                }
    } else {
        const int e8 = (KIND == 1) ? (((bn >> 2) << 3) + ((bn & 3) << 1) + wc)
                                   : ((z << 3) + (bn << 1) + wc);
        #pragma unroll
        for (int fm = 0; fm < 4; ++fm) {
            float rs[4] = {0.f, 0.f, 0.f, 0.f};
            #pragma unroll
            for (int fn = 0; fn < 4; ++fn)
                #pragma unroll
                for (int j = 0; j < 4; ++j) {
                    float v = acc[fm][fn][j] + accB_[fm][fn][j] * ILOSC;
                    long row = rB + fm * 16 + lr_ + j;
                    long col = cB + fn * 16 + lc_;
                    if constexpr (KIND == 1) {
                        long idx = row * (long)DIN + col;
                        f16 h = (f16)v;
                        Chi[idx] = h;
                        Clo[idx] = (f16)((v - (float)h) * LOSC);
                        rs[j] += v * v;
                    } else {
                        long tidx = row * (long)DIN + (long)z * RNK + col;
                        float tv = (float)Th[tidx] + (float)Tl[tidx] * ILOSC;
                        rs[j] += v * tv;
                    }
                }
            #pragma unroll
            for (int j = 0; j < 4; ++j) {
                float s = rs[j];
                s += __shfl_xor(s, 1, 64);
                s += __shfl_xor(s, 2, 64);
                s += __shfl_xor(s, 4, 64);
                s += __shfl_xor(s, 8, 64);
                if (lc_ == 0) {
                    long row = rB + fm * 16 + lr_ + j;
                    rowp[row * 64 + e8] = s;
                }
            }
        }
    }
}

// ---------------------------------------------------------------------------
// 256x256 MFMA GEMM, ring-4 LDS pipeline (BK=32, stage-ahead 3), 512 threads
// (8 waves = 2M x 4N), XCD-bijective-swizzled 1D grid, bm-innermost decode.
// Per step: vmcnt(8); s_barrier; sched_barrier; stage tile s+3 (4 gload_lds);
// 12 ds_read_b128 + 32 MFMA (setprio-wrapped). LDS: 4 x [A|B][256][32] = 128 KiB.
// KIND 3: pretrained dense -> fp32 out + bias[n]
// KIND 4: expert gather    -> f16 Yg rows via toklist, z = expert, bias[z][n]
// ---------------------------------------------------------------------------
template<int KIND>
__global__ __launch_bounds__(512, 1) void gemm256_k(
    const f16* __restrict__ A, const f16* __restrict__ Bm,
    float* __restrict__ Cf, f16* __restrict__ Ch, const float* __restrict__ bias,
    const int* __restrict__ toklist, const int* __restrict__ cnt, const int* __restrict__ offs,
    int Mtiles, int Ntiles)
{
    // bijective XCD swizzle (m204): each XCD gets a contiguous logical range
    const int nwg = gridDim.x;
    const int orig = blockIdx.x;
    const int qq = nwg >> 3, rr8 = nwg & 7;
    const int xcd = orig & 7, pos = orig >> 3;
    const int wg = (xcd < rr8 ? xcd * (qq + 1) : rr8 * (qq + 1) + (xcd - rr8) * qq) + pos;
    const int bm = wg % Mtiles;
    const int rest = wg / Mtiles;
    const int bn = rest % Ntiles;
    const int z  = rest / Ntiles;

    const int tid = threadIdx.x;
    const int lane = tid & 63, wv = tid >> 6;
    const int wr = wv >> 2, wc = wv & 3;          // 2 x 4 wave grid
    const int m0 = bm * 256, n0 = bn * 256;

    int cntz = 0, offz = 0;
    if constexpr (KIND == 4) {
        cntz = cnt[z]; offz = offs[z];
        if (m0 >= cntz) return;
    }

    __shared__ f16 smem[65536];                   // 4 slots x 16384 f16: [A 0][B 8192]

    long bBase = 0;
    if constexpr (KIND == 4) bBase = (long)z * DOUT * DIN;

    // per-thread staging sources (linear): g=j*512+tid, r=g>>2 in [0,256), u=g&3
    long srcA2[2], srcB2[2];
    #pragma unroll
    for (int j = 0; j < 2; ++j) {
        int g = j * 512 + tid;
        int r = g >> 2, u = g & 3;
        if constexpr (KIND == 4) {
            int rg = m0 + r;
            int tok = (rg < cntz) ? toklist[offz + rg] : 0;
            srcA2[j] = (long)tok * DIN + u * 8;
        } else {
            srcA2[j] = (long)(m0 + r) * DIN + u * 8;
        }
        srcB2[j] = bBase + (long)(n0 + r) * DIN + u * 8;
    }

    auto stage = [&](int slot, int kOff) {
        const int e0 = slot * 16384;
        #pragma unroll
        for (int j = 0; j < 2; ++j) {
            int g = j * 512 + tid;
            __builtin_amdgcn_global_load_lds((const AS1 void*)(A + srcA2[j] + kOff),
                (AS3 void*)(&smem[e0 + g * 8]), 16, 0, 0);
            __builtin_amdgcn_global_load_lds((const AS1 void*)(Bm + srcB2[j] + kOff),
                (AS3 void*)(&smem[e0 + 8192 + g * 8]), 16, 0, 0);
        }
    };

    f32x4 acc[8][4];
    #pragma unroll
    for (int a = 0; a < 8; ++a)
        #pragma unroll
        for (int b = 0; b < 4; ++b) acc[a][b] = f32x4{0.f, 0.f, 0.f, 0.f};

    const int q = lane >> 4, li = lane & 15;

    // prologue: tiles 0,1,2 in flight (12 loads)
    stage(0, 0);
    stage(1, 32);
    stage(2, 64);

    for (int t = 0; t < 128; t += 4) {
        #pragma unroll
        for (int uu = 0; uu < 4; ++uu) {
            const int s = t + uu;
            const int ts = (s + 3 < 128) ? s + 3 : 127;
            asm volatile("s_waitcnt vmcnt(8)" ::: "memory"); // tile s landed; s+1,s+2 in flight
            __builtin_amdgcn_s_barrier();
            __builtin_amdgcn_sched_barrier(0);
            stage((uu + 3) & 3, ts * 32);
            const char* base = (const char*)smem + uu * 32768;
            f16x8 bhf[4];
            #pragma unroll
            for (int fn = 0; fn < 4; ++fn) {
                int rb = wc * 64 + fn * 16 + li;
                bhf[fn] = *(const f16x8*)(base + 16384 + rb * 64 + q * 16);
            }
            __builtin_amdgcn_s_setprio(1);
            #pragma unroll
            for (int fm = 0; fm < 8; ++fm) {
                int ra = wr * 128 + fm * 16 + li;
                f16x8 ahf = *(const f16x8*)(base + ra * 64 + q * 16);
                #pragma unroll
                for (int fn = 0; fn < 4; ++fn)
                    acc[fm][fn] = __builtin_amdgcn_mfma_f32_16x16x32_f16(ahf, bhf[fn], acc[fm][fn], 0, 0, 0);
            }
            __builtin_amdgcn_s_setprio(0);
        }
    }

    const int lr_ = (lane >> 4) * 4;
    const int lc_ = lane & 15;
    #pragma unroll
    for (int fm = 0; fm < 8; ++fm)
        #pragma unroll
        for (int fn = 0; fn < 4; ++fn)
            #pragma unroll
            for (int j = 0; j < 4; ++j) {
                int rloc = wr * 128 + fm * 16 + lr_ + j;
                long col = n0 + wc * 64 + fn * 16 + lc_;
                if constexpr (KIND == 4) {
                    if (m0 + rloc < cntz) {
                        long row = (long)offz + m0 + rloc;
                        Ch[row * (long)DOUT + col] = (f16)(acc[fm][fn][j] + bias[(long)z * DOUT + col]);
                    }
                } else {
                    long row = m0 + rloc;
                    Cf[row * (long)DOUT + col] = acc[fm][fn][j] + bias[col];
                }
            }
}

// ---------------------------------------------------------------------------
// routing: residual^2 = ||x||^2 - 2||t||^2 + tGt ; softmax(-r) ; top-2 & >1/8 mask
// ---------------------------------------------------------------------------
__global__ __launch_bounds__(256) void route_k(const double* __restrict__ normx,
    const float* __restrict__ rowpT, const float* __restrict__ rowpU,
    int* __restrict__ cnt, int* __restrict__ toke, float* __restrict__ tokw)
{
    const int i = blockIdx.x * 256 + threadIdx.x;
    if (i >= NTOK) return;
    const double nx = normx[i];
    double r[NE];
    #pragma unroll
    for (int e = 0; e < NE; ++e) {
        double tn = 0.0, s2 = 0.0;
        #pragma unroll
        for (int s = 0; s < 8; ++s) {
            tn += (double)rowpT[(long)i * 64 + e * 8 + s];
            s2 += (double)rowpU[(long)i * 64 + e * 8 + s];
        }
        double r2 = nx - 2.0 * tn + s2;
        r[e] = sqrt(r2 > 0.0 ? r2 : 0.0);
    }
    double rmin = r[0];
    #pragma unroll
    for (int e = 1; e < NE; ++e) if (r[e] < rmin) rmin = r[e];
    double w[NE], S = 0.0;
    #pragma unroll
    for (int e = 0; e < NE; ++e) { w[e] = exp(rmin - r[e]); S += w[e]; }
    double rw[NE];
    #pragma unroll
    for (int e = 0; e < NE; ++e) rw[e] = w[e] / S;
    // top-2, first-occurrence tie-break (matches lax.top_k)
    int i1 = 0;
    #pragma unroll
    for (int e = 1; e < NE; ++e) if (rw[e] > rw[i1]) i1 = e;
    int i2 = (i1 == 0) ? 1 : 0;
    #pragma unroll
    for (int e = 0; e < NE; ++e) if (e != i2 && e != i1 && rw[e] > rw[i2]) i2 = e;
    double f1 = (rw[i1] > 0.125) ? rw[i1] : 0.0;
    double f2 = (rw[i2] > 0.125) ? rw[i2] : 0.0;
    double s = f1 + f2;
    int e0 = -1, e1 = -1; float w0 = 0.f, w1 = 0.f;
    if (s > 0.0) {
        if (f1 > 0.0) { e0 = i1; w0 = (float)(f1 / s); }
        if (f2 > 0.0) { e1 = i2; w1 = (float)(f2 / s); }
    }
    toke[i * 2 + 0] = e0; toke[i * 2 + 1] = e1;
    tokw[i * 2 + 0] = w0; tokw[i * 2 + 1] = w1;
    if (e0 >= 0) atomicAdd(&cnt[e0], 1);
    if (e1 >= 0) atomicAdd(&cnt[e1], 1);
}

__global__ void offs_k(const int* __restrict__ cnt, int* __restrict__ offs)
{
    if (threadIdx.x == 0) {
        int a = 0;
        for (int e = 0; e < NE; ++e) { offs[e] = a; a += cnt[e]; }
    }
}

__global__ __launch_bounds__(256) void assign_k(const int* __restrict__ toke,
    const int* __restrict__ offs, int* __restrict__ cur,
    int* __restrict__ toklist, int* __restrict__ tokslot)
{
    const int i = blockIdx.x * 256 + threadIdx.x;
    if (i >= NTOK) return;
    #pragma unroll
    for (int j = 0; j < 2; ++j) {
        int e = toke[i * 2 + j];
        if (e >= 0) {
            int p = atomicAdd(&cur[e], 1);
            int sl = offs[e] + p;
            toklist[sl] = i;
            tokslot[i * 2 + j] = sl;
        } else {
            tokslot[i * 2 + j] = -1;
        }
    }
}

__global__ __launch_bounds__(256) void combine_k(float* __restrict__ out,
    const f16* __restrict__ Yg, const int* __restrict__ tokslot, const float* __restrict__ tokw)
{
    const int i = blockIdx.x;
    int s0 = tokslot[i * 2 + 0], s1 = tokslot[i * 2 + 1];
    float w0 = (s0 >= 0) ? tokw[i * 2 + 0] : 0.f;
    float w1 = (s1 >= 0) ? tokw[i * 2 + 1] : 0.f;
    const f16x4* y0 = (const f16x4*)(Yg + (size_t)(s0 < 0 ? 0 : s0) * DOUT);
    const f16x4* y1 = (const f16x4*)(Yg + (size_t)(s1 < 0 ? 0 : s1) * DOUT);
    float4* o = (float4*)(out + (size_t)i * DOUT);
    for (int c = threadIdx.x; c < DOUT / 4; c += 256) {
        float4 v = o[c];
        f16x4 a = y0[c], b = y1[c];
        v.x += w0 * (float)a[0] + w1 * (float)b[0];
        v.y += w0 * (float)a[1] + w1 * (float)b[1];
        v.z += w0 * (float)a[2] + w1 * (float)b[2];
        v.w += w0 * (float)a[3] + w1 * (float)b[3];
        o[c] = v;
    }
}

// ---------------------------------------------------------------------------
extern "C" void kernel_launch(void* const* d_in, const int* in_sizes, int n_in,
                              void* d_out, int out_size, void* d_ws, size_t ws_size,
                              hipStream_t stream)
{
    const float* X  = (const float*)d_in[0];
    const float* GW = (const float*)d_in[1];
    const float* Wp = (const float*)d_in[2];
    const float* bp = (const float*)d_in[3];
    const float* We = (const float*)d_in[4];
    const float* be = (const float*)d_in[5];
    float* out = (float*)d_out;

    char* ws = (char*)d_ws;
    size_t o = 0;
    auto alloc = [&](size_t bytes) { char* p = ws + o; o += (bytes + 255) & ~(size_t)255; return p; };

    f16* Xhi = (f16*)alloc((size_t)NTOK * DIN * 2);
    const size_t aliasOff = o;                      // Yg aliases [Xlo..Tlo] (all dead by expert GEMM)
    f16* Xlo  = (f16*)alloc((size_t)NTOK * DIN * 2);
    f16* GThi = (f16*)alloc((size_t)NE * RNK * DIN * 2);
    f16* GTlo = (f16*)alloc((size_t)NE * RNK * DIN * 2);
    f16* Thi  = (f16*)alloc((size_t)NTOK * DIN * 2);
    f16* Tlo  = (f16*)alloc((size_t)NTOK * DIN * 2);
    f16* Yg = (f16*)(ws + aliasOff);                // 2*NTOK x DOUT f16 = 134 MB (fits alias span)
    f16* Wp16 = (f16*)alloc((size_t)DOUT * DIN * 2);
    f16* We16 = (f16*)alloc((size_t)NE * DOUT * DIN * 2);
    f16* Ghi  = (f16*)alloc((size_t)NE * RNK * RNK * 2);
    f16* Glo  = (f16*)alloc((size_t)NE * RNK * RNK * 2);
    double* normx = (double*)alloc((size_t)NTOK * 8);
    float* rowpT  = (float*)alloc((size_t)NTOK * 64 * 4);
    float* rowpU  = (float*)alloc((size_t)NTOK * 64 * 4);
    float* tokw   = (float*)alloc((size_t)NTOK * 2 * 4);
    int* toke     = (int*)alloc((size_t)NTOK * 2 * 4);
    int* tokslot  = (int*)alloc((size_t)NTOK * 2 * 4);
    int* toklist  = (int*)alloc((size_t)2 * NTOK * 4);
    int* cnt      = (int*)alloc(64 * 4);
    int* offs = cnt + 8;
    int* cur  = cnt + 16;

    if (ws_size < o) return; // ws too small -> output stays zero (visible failure)

    hipMemsetAsync(cnt, 0, 64 * 4, stream);

    split_x_k<<<NTOK, 256, 0, stream>>>(X, Xhi, Xlo, normx);
    trans_gate_k<<<dim3(RNK / 64, DIN / 64, NE), 256, 0, stream>>>(GW, GThi, GTlo);
    conv16_k<<<2048, 256, 0, stream>>>(Wp, Wp16, (long)DOUT * DIN / 4);
    conv16_k<<<4096, 256, 0, stream>>>(We, We16, (long)NE * DOUT * DIN / 4);

    // G = V^T V (split precision)
    gemm_k<0><<<dim3(4, 4, NE), 256, 0, stream>>>(GThi, GTlo, GThi, GTlo,
        Ghi, Glo, nullptr, nullptr, nullptr);
    // T = X V (split) + ||t||^2 partials  (1-D XCD-swizzled grid)
    gemm_k<1><<<2048, 256, 0, stream>>>(Xhi, Xlo, GThi, GTlo,
        Thi, Tlo, rowpT, nullptr, nullptr);
    // s2 = t G t^T partials (split)
    gemm_k<2><<<dim3(64, 4, NE), 256, 0, stream>>>(Thi, Tlo, Ghi, Glo,
        nullptr, nullptr, rowpU, Thi, Tlo);

    route_k<<<NTOK / 256, 256, 0, stream>>>(normx, rowpT, rowpU, cnt, toke, tokw);
    offs_k<<<1, 1, 0, stream>>>(cnt, offs);
    assign_k<<<NTOK / 256, 256, 0, stream>>>(toke, offs, cur, toklist, tokslot);

    // pretrained: out = X Wp^T + bp   (256^2 tile, XCD-swizzled, ring-4)
    gemm256_k<3><<<32 * 16, 512, 0, stream>>>(Xhi, Wp16,
        out, nullptr, bp, nullptr, nullptr, nullptr, 32, 16);
    // experts (gathered rows): Yg[slot] = f16(X[tok] We^T + be)
    gemm256_k<4><<<NE * 32 * 16, 512, 0, stream>>>(Xhi, We16,
        nullptr, Yg, be, toklist, cnt, offs, 32, 16);

    combine_k<<<NTOK, 256, 0, stream>>>(out, Yg, tokslot, tokw);
}

// Round 7
// 2658.360 us; speedup vs baseline: 1.0582x; 1.0212x over previous
//
#include <hip/hip_runtime.h>

typedef _Float16 f16;
typedef _Float16 f16x4 __attribute__((ext_vector_type(4)));
typedef _Float16 f16x8 __attribute__((ext_vector_type(8)));
typedef float    f32x4 __attribute__((ext_vector_type(4)));

static constexpr int NTOK = 8192;
static constexpr int DIN  = 4096;
static constexpr int DOUT = 4096;
static constexpr int NE   = 8;
static constexpr int RNK  = 512;
static constexpr float LOSC  = 2048.0f;   // lo terms stored pre-scaled by 2^11 (fp16 denormal dodge)
static constexpr float ILOSC = 1.0f/2048.0f;

#define AS1 __attribute__((address_space(1)))
#define AS3 __attribute__((address_space(3)))

// ---------------------------------------------------------------------------
// split hidden_states into fp16 hi/lo and compute ||x||^2 per row (double)
// ---------------------------------------------------------------------------
__global__ __launch_bounds__(256) void split_x_k(const float* __restrict__ X,
    f16* __restrict__ Xhi, f16* __restrict__ Xlo, double* __restrict__ normx)
{
    const int row = blockIdx.x, tid = threadIdx.x;
    const float4* xr = (const float4*)(X + (size_t)row * DIN);
    f16x4* hr = (f16x4*)(Xhi + (size_t)row * DIN);
    f16x4* lr = (f16x4*)(Xlo + (size_t)row * DIN);
    double acc = 0.0;
    #pragma unroll
    for (int it = 0; it < 4; ++it) {
        int i = tid + it * 256;
        float4 v = xr[i];
        float vv[4] = {v.x, v.y, v.z, v.w};
        f16x4 h, l;
        #pragma unroll
        for (int j = 0; j < 4; ++j) {
            f16 hh = (f16)vv[j];
            h[j] = hh;
            l[j] = (f16)((vv[j] - (float)hh) * LOSC);
            acc += (double)vv[j] * (double)vv[j];
        }
        hr[i] = h; lr[i] = l;
    }
    #pragma unroll
    for (int m = 1; m < 64; m <<= 1) acc += __shfl_xor(acc, m, 64);
    __shared__ double sred[4];
    if ((tid & 63) == 0) sred[tid >> 6] = acc;
    __syncthreads();
    if (tid == 0) normx[row] = sred[0] + sred[1] + sred[2] + sred[3];
}

// ---------------------------------------------------------------------------
// transpose gate_weight [E][D][R] fp32 -> GT [E][R][D] fp16 hi/lo (row-major, K contiguous)
// ---------------------------------------------------------------------------
__global__ __launch_bounds__(256) void trans_gate_k(const float* __restrict__ GW,
    f16* __restrict__ GThi, f16* __restrict__ GTlo)
{
    __shared__ float t[64][65];
    const int e = blockIdx.z;
    const int r0 = blockIdx.x * 64, d0 = blockIdx.y * 64;
    const float* src = GW + (size_t)e * DIN * RNK;
    const int c = threadIdx.x & 63, rq = threadIdx.x >> 6;
    #pragma unroll
    for (int i = 0; i < 16; ++i) {
        int dr = i * 4 + rq;
        t[dr][c] = src[(size_t)(d0 + dr) * RNK + r0 + c];
    }
    __syncthreads();
    const size_t obase = (size_t)e * RNK * DIN;
    #pragma unroll
    for (int i = 0; i < 16; ++i) {
        int rr = i * 4 + rq;
        float v = t[c][rr];
        f16 h = (f16)v;
        size_t idx = obase + (size_t)(r0 + rr) * DIN + d0 + c;
        GThi[idx] = h;
        GTlo[idx] = (f16)((v - (float)h) * LOSC);
    }
}

// ---------------------------------------------------------------------------
// fp32 -> fp16 elementwise convert (weights; single precision level is enough)
// ---------------------------------------------------------------------------
__global__ __launch_bounds__(256) void conv16_k(const float* __restrict__ src,
    f16* __restrict__ dst, long n4)
{
    long i = (long)blockIdx.x * 256 + threadIdx.x;
    const long stride = (long)gridDim.x * 256;
    for (; i < n4; i += stride) {
        float4 v = ((const float4*)src)[i];
        f16x4 h = { (f16)v.x, (f16)v.y, (f16)v.z, (f16)v.w };
        ((f16x4*)dst)[i] = h;
    }
}

// ---------------------------------------------------------------------------
// Split-precision 128x128 MFMA GEMM, ring-4 LDS pipeline (BK=32, stage-ahead 3),
// granule-swizzled LDS (g = q ^ ((row>>1)&3); pre-swizzled global src, linear dest):
// per step: vmcnt(16); s_barrier; sched_barrier; stage tile s+3 (8 gload_lds);
// 16 ds_read_b128 + 48 MFMA. LDS: 4 slots x [Ah|Bh|Al|Bl][128][32] f16 = 128 KiB.
// KIND 0: G = V^T V      (M=N=512, K=4096, z=expert) -> Ghi/Glo
// KIND 1: T = X Vt^T     (M=8192, N=4096, K=4096) -> Thi/Tlo + rowpT; XCD swizzle
// KIND 2: s2 = sum((TG) o T) (M=8192, N=512 per e, K=512, z=expert) -> rowpU
// ---------------------------------------------------------------------------
template<int KIND>
__global__ __launch_bounds__(256, 1) void gemm_k(
    const f16* __restrict__ Ah, const f16* __restrict__ Al,
    const f16* __restrict__ Bh, const f16* __restrict__ Bl,
    f16* __restrict__ Chi, f16* __restrict__ Clo,
    float* __restrict__ rowp,
    const f16* __restrict__ Th, const f16* __restrict__ Tl)
{
    constexpr int KDIM = (KIND == 2) ? 512 : 4096;
    constexpr int LDB  = (KIND == 2) ? 512 : 4096;
    constexpr int NT   = KDIM / 32;

    int bm, bn, z;
    if constexpr (KIND == 1) {
        // bijective XCD swizzle: 2048 blocks, 8 XCDs, 256/chunk; bm-innermost
        const int orig = blockIdx.x;
        const int wg = (orig & 7) * 256 + (orig >> 3);
        bm = wg & 63; bn = wg >> 6; z = 0;
    } else {
        bm = blockIdx.x; bn = blockIdx.y; z = blockIdx.z;
    }
    const int tid = threadIdx.x;
    const int lane = tid & 63, wv = tid >> 6;
    const int wr = wv >> 1, wc = wv & 1;
    const int m0 = bm * 128, n0 = bn * 128;

    __shared__ f16 smem[65536]; // 4 slots x 16384 f16: [Ah 0][Bh 4096][Al 8192][Bl 12288]

    long aBase = 0, bBase = 0;
    if constexpr (KIND == 0) { aBase = (long)z * RNK * DIN; bBase = aBase; }
    if constexpr (KIND == 2) { aBase = (long)z * RNK; bBase = (long)z * RNK * RNK; }

    // per-thread staging sources (pre-swizzled granule): g=j*256+tid, r=g>>2, u=g&3
    long s2A[2], s2B[2];
    #pragma unroll
    for (int j = 0; j < 2; ++j) {
        int g = j * 256 + tid;
        int r = g >> 2, u = g & 3;
        int sc = (u ^ ((r >> 1) & 3)) * 8;   // granule swizzle (f16 elems)
        s2A[j] = aBase + (long)(m0 + r) * DIN + sc;
        s2B[j] = bBase + (long)(n0 + r) * LDB + sc;
    }

    auto stage = [&](int slot, int kOff) {
        const int e0 = slot * 16384;
        #pragma unroll
        for (int j = 0; j < 2; ++j) {
            int g = j * 256 + tid;
            __builtin_amdgcn_global_load_lds((const AS1 void*)(Ah + s2A[j] + kOff),
                (AS3 void*)(&smem[e0 + g * 8]), 16, 0, 0);
            __builtin_amdgcn_global_load_lds((const AS1 void*)(Bh + s2B[j] + kOff),
                (AS3 void*)(&smem[e0 + 4096 + g * 8]), 16, 0, 0);
            __builtin_amdgcn_global_load_lds((const AS1 void*)(Al + s2A[j] + kOff),
                (AS3 void*)(&smem[e0 + 8192 + g * 8]), 16, 0, 0);
            __builtin_amdgcn_global_load_lds((const AS1 void*)(Bl + s2B[j] + kOff),
                (AS3 void*)(&smem[e0 + 12288 + g * 8]), 16, 0, 0);
        }
    };

    f32x4 acc[4][4], accB_[4][4];
    #pragma unroll
    for (int a = 0; a < 4; ++a)
        #pragma unroll
        for (int b = 0; b < 4; ++b) {
            acc[a][b]   = f32x4{0.f, 0.f, 0.f, 0.f};
            accB_[a][b] = f32x4{0.f, 0.f, 0.f, 0.f};
        }

    const int q = lane >> 4, li = lane & 15;

    // prologue: tiles 0,1,2 in flight (24 loads)
    stage(0, 0);
    stage(1, 32);
    stage(2, 64);

    for (int t = 0; t < NT; t += 4) {
        #pragma unroll
        for (int uu = 0; uu < 4; ++uu) {
            const int s = t + uu;
            const int ts = (s + 3 < NT) ? s + 3 : NT - 1;   // tail: dead re-stage keeps vmcnt uniform
            asm volatile("s_waitcnt vmcnt(16)" ::: "memory"); // tile s landed; s+1,s+2 in flight
            __builtin_amdgcn_s_barrier();                     // landing + prior reads global
            __builtin_amdgcn_sched_barrier(0);
            stage((uu + 3) & 3, ts * 32);
            const char* base = (const char*)smem + uu * 32768;
            f16x8 bhf[4], blf[4];
            #pragma unroll
            for (int fn = 0; fn < 4; ++fn) {
                int rb = wc * 64 + fn * 16 + li;
                int off = rb * 64 + ((q ^ ((rb >> 1) & 3)) << 4);
                bhf[fn] = *(const f16x8*)(base + 8192 + off);
                blf[fn] = *(const f16x8*)(base + 24576 + off);
            }
            __builtin_amdgcn_s_setprio(1);
            #pragma unroll
            for (int fm = 0; fm < 4; ++fm) {
                int ra = wr * 64 + fm * 16 + li;
                int offA = ra * 64 + ((q ^ ((ra >> 1) & 3)) << 4);
                f16x8 ahf = *(const f16x8*)(base + offA);
                f16x8 alv = *(const f16x8*)(base + 16384 + offA);
                #pragma unroll
                for (int fn = 0; fn < 4; ++fn) {
                    acc[fm][fn]   = __builtin_amdgcn_mfma_f32_16x16x32_f16(ahf, bhf[fn], acc[fm][fn],   0, 0, 0);
                    accB_[fm][fn] = __builtin_amdgcn_mfma_f32_16x16x32_f16(ahf, blf[fn], accB_[fm][fn], 0, 0, 0);
                    accB_[fm][fn] = __builtin_amdgcn_mfma_f32_16x16x32_f16(alv, bhf[fn], accB_[fm][fn], 0, 0, 0);
                }
            }
            __builtin_amdgcn_s_setprio(0);
        }
    }

    const int lr_ = (lane >> 4) * 4;
    const int lc_ = lane & 15;
    const int rB = m0 + wr * 64;
    const int cB = n0 + wc * 64;

    if constexpr (KIND == 0) {
        #pragma unroll
        for (int fm = 0; fm < 4; ++fm)
            #pragma unroll
            for (int fn = 0; fn < 4; ++fn)
                #pragma unroll
                for (int j = 0; j < 4; ++j) {
                    float v = acc[fm][fn][j] + accB_[fm][fn][j] * ILOSC;
                    long row = rB + fm * 16 + lr_ + j;
                    long col = cB + fn * 16 + lc_;
                    long idx = (long)z * RNK * RNK + row * RNK + col;
                    f16 h = (f16)v;
                    Chi[idx] = h;
                    Clo[idx] = (f16)((v - (float)h) * LOSC);
                }
    } else {
        const int e8 = (KIND == 1) ? (((bn >> 2) << 3) + ((bn & 3) << 1) + wc)
                                   : ((z << 3) + (bn << 1) + wc);
        #pragma unroll
        for (int fm = 0; fm < 4; ++fm) {
            float rs[4] = {0.f, 0.f, 0.f, 0.f};
            #pragma unroll
            for (int fn = 0; fn < 4; ++fn)
                #pragma unroll
                for (int j = 0; j < 4; ++j) {
                    float v = acc[fm][fn][j] + accB_[fm][fn][j] * ILOSC;
                    long row = rB + fm * 16 + lr_ + j;
                    long col = cB + fn * 16 + lc_;
                    if constexpr (KIND == 1) {
                        long idx = row * (long)DIN + col;
                        f16 h = (f16)v;
                        Chi[idx] = h;
                        Clo[idx] = (f16)((v - (float)h) * LOSC);
                        rs[j] += v * v;
                    } else {
                        long tidx = row * (long)DIN + (long)z * RNK + col;
                        float tv = (float)Th[tidx] + (float)Tl[tidx] * ILOSC;
                        rs[j] += v * tv;
                    }
                }
            #pragma unroll
            for (int j = 0; j < 4; ++j) {
                float s = rs[j];
                s += __shfl_xor(s, 1, 64);
                s += __shfl_xor(s, 2, 64);
                s += __shfl_xor(s, 4, 64);
                s += __shfl_xor(s, 8, 64);
                if (lc_ == 0) {
                    long row = rB + fm * 16 + lr_ + j;
                    rowp[row * 64 + e8] = s;
                }
            }
        }
    }
}

// ---------------------------------------------------------------------------
// 256x256 MFMA GEMM, ring-4 LDS pipeline (BK=32, stage-ahead 3), 512 threads
// (8 waves = 2M x 4N), granule-swizzled LDS, XCD-bijective-swizzled 1D grid.
// Per step: vmcnt(8); s_barrier; sched_barrier; stage tile s+3 (4 gload_lds);
// 12 ds_read_b128 + 32 MFMA (setprio-wrapped). LDS: 4 x [A|B][256][32] = 128 KiB.
// KIND 3: pretrained dense -> fp32 out + bias[n]
// KIND 4: expert gather    -> f16 Yg rows via toklist, z = expert, bias[z][n]
// ---------------------------------------------------------------------------
template<int KIND>
__global__ __launch_bounds__(512, 1) void gemm256_k(
    const f16* __restrict__ A, const f16* __restrict__ Bm,
    float* __restrict__ Cf, f16* __restrict__ Ch, const float* __restrict__ bias,
    const int* __restrict__ toklist, const int* __restrict__ cnt, const int* __restrict__ offs,
    int Mtiles, int Ntiles)
{
    // bijective XCD swizzle (m204): each XCD gets a contiguous logical range
    const int nwg = gridDim.x;
    const int orig = blockIdx.x;
    const int qq = nwg >> 3, rr8 = nwg & 7;
    const int xcd = orig & 7, pos = orig >> 3;
    const int wg = (xcd < rr8 ? xcd * (qq + 1) : rr8 * (qq + 1) + (xcd - rr8) * qq) + pos;
    const int bm = wg % Mtiles;
    const int rest = wg / Mtiles;
    const int bn = rest % Ntiles;
    const int z  = rest / Ntiles;

    const int tid = threadIdx.x;
    const int lane = tid & 63, wv = tid >> 6;
    const int wr = wv >> 2, wc = wv & 3;          // 2 x 4 wave grid
    const int m0 = bm * 256, n0 = bn * 256;

    int cntz = 0, offz = 0;
    if constexpr (KIND == 4) {
        cntz = cnt[z]; offz = offs[z];
        if (m0 >= cntz) return;
    }

    __shared__ f16 smem[65536];                   // 4 slots x 16384 f16: [A 0][B 8192]

    long bBase = 0;
    if constexpr (KIND == 4) bBase = (long)z * DOUT * DIN;

    // per-thread staging sources (pre-swizzled granule): g=j*512+tid, r=g>>2, u=g&3
    long srcA2[2], srcB2[2];
    #pragma unroll
    for (int j = 0; j < 2; ++j) {
        int g = j * 512 + tid;
        int r = g >> 2, u = g & 3;
        int sc = (u ^ ((r >> 1) & 3)) * 8;        // granule swizzle (f16 elems)
        if constexpr (KIND == 4) {
            int rg = m0 + r;
            int tok = (rg < cntz) ? toklist[offz + rg] : 0;
            srcA2[j] = (long)tok * DIN + sc;
        } else {
            srcA2[j] = (long)(m0 + r) * DIN + sc;
        }
        srcB2[j] = bBase + (long)(n0 + r) * DIN + sc;
    }

    auto stage = [&](int slot, int kOff) {
        const int e0 = slot * 16384;
        #pragma unroll
        for (int j = 0; j < 2; ++j) {
            int g = j * 512 + tid;
            __builtin_amdgcn_global_load_lds((const AS1 void*)(A + srcA2[j] + kOff),
                (AS3 void*)(&smem[e0 + g * 8]), 16, 0, 0);
            __builtin_amdgcn_global_load_lds((const AS1 void*)(Bm + srcB2[j] + kOff),
                (AS3 void*)(&smem[e0 + 8192 + g * 8]), 16, 0, 0);
        }
    };

    f32x4 acc[8][4];
    #pragma unroll
    for (int a = 0; a < 8; ++a)
        #pragma unroll
        for (int b = 0; b < 4; ++b) acc[a][b] = f32x4{0.f, 0.f, 0.f, 0.f};

    const int q = lane >> 4, li = lane & 15;

    // prologue: tiles 0,1,2 in flight (12 loads)
    stage(0, 0);
    stage(1, 32);
    stage(2, 64);

    for (int t = 0; t < 128; t += 4) {
        #pragma unroll
        for (int uu = 0; uu < 4; ++uu) {
            const int s = t + uu;
            const int ts = (s + 3 < 128) ? s + 3 : 127;
            asm volatile("s_waitcnt vmcnt(8)" ::: "memory"); // tile s landed; s+1,s+2 in flight
            __builtin_amdgcn_s_barrier();
            __builtin_amdgcn_sched_barrier(0);
            stage((uu + 3) & 3, ts * 32);
            const char* base = (const char*)smem + uu * 32768;
            f16x8 bhf[4];
            #pragma unroll
            for (int fn = 0; fn < 4; ++fn) {
                int rb = wc * 64 + fn * 16 + li;
                bhf[fn] = *(const f16x8*)(base + 16384 + rb * 64 + ((q ^ ((rb >> 1) & 3)) << 4));
            }
            __builtin_amdgcn_s_setprio(1);
            #pragma unroll
            for (int fm = 0; fm < 8; ++fm) {
                int ra = wr * 128 + fm * 16 + li;
                f16x8 ahf = *(const f16x8*)(base + ra * 64 + ((q ^ ((ra >> 1) & 3)) << 4));
                #pragma unroll
                for (int fn = 0; fn < 4; ++fn)
                    acc[fm][fn] = __builtin_amdgcn_mfma_f32_16x16x32_f16(ahf, bhf[fn], acc[fm][fn], 0, 0, 0);
            }
            __builtin_amdgcn_s_setprio(0);
        }
    }

    const int lr_ = (lane >> 4) * 4;
    const int lc_ = lane & 15;
    #pragma unroll
    for (int fm = 0; fm < 8; ++fm)
        #pragma unroll
        for (int fn = 0; fn < 4; ++fn)
            #pragma unroll
            for (int j = 0; j < 4; ++j) {
                int rloc = wr * 128 + fm * 16 + lr_ + j;
                long col = n0 + wc * 64 + fn * 16 + lc_;
                if constexpr (KIND == 4) {
                    if (m0 + rloc < cntz) {
                        long row = (long)offz + m0 + rloc;
                        Ch[row * (long)DOUT + col] = (f16)(acc[fm][fn][j] + bias[(long)z * DOUT + col]);
                    }
                } else {
                    long row = m0 + rloc;
                    Cf[row * (long)DOUT + col] = acc[fm][fn][j] + bias[col];
                }
            }
}

// ---------------------------------------------------------------------------
// routing: residual^2 = ||x||^2 - 2||t||^2 + tGt ; softmax(-r) ; top-2 & >1/8 mask
// ---------------------------------------------------------------------------
__global__ __launch_bounds__(256) void route_k(const double* __restrict__ normx,
    const float* __restrict__ rowpT, const float* __restrict__ rowpU,
    int* __restrict__ cnt, int* __restrict__ toke, float* __restrict__ tokw)
{
    const int i = blockIdx.x * 256 + threadIdx.x;
    if (i >= NTOK) return;
    const double nx = normx[i];
    double r[NE];
    #pragma unroll
    for (int e = 0; e < NE; ++e) {
        double tn = 0.0, s2 = 0.0;
        #pragma unroll
        for (int s = 0; s < 8; ++s) {
            tn += (double)rowpT[(long)i * 64 + e * 8 + s];
            s2 += (double)rowpU[(long)i * 64 + e * 8 + s];
        }
        double r2 = nx - 2.0 * tn + s2;
        r[e] = sqrt(r2 > 0.0 ? r2 : 0.0);
    }
    double rmin = r[0];
    #pragma unroll
    for (int e = 1; e < NE; ++e) if (r[e] < rmin) rmin = r[e];
    double w[NE], S = 0.0;
    #pragma unroll
    for (int e = 0; e < NE; ++e) { w[e] = exp(rmin - r[e]); S += w[e]; }
    double rw[NE];
    #pragma unroll
    for (int e = 0; e < NE; ++e) rw[e] = w[e] / S;
    // top-2, first-occurrence tie-break (matches lax.top_k)
    int i1 = 0;
    #pragma unroll
    for (int e = 1; e < NE; ++e) if (rw[e] > rw[i1]) i1 = e;
    int i2 = (i1 == 0) ? 1 : 0;
    #pragma unroll
    for (int e = 0; e < NE; ++e) if (e != i2 && e != i1 && rw[e] > rw[i2]) i2 = e;
    double f1 = (rw[i1] > 0.125) ? rw[i1] : 0.0;
    double f2 = (rw[i2] > 0.125) ? rw[i2] : 0.0;
    double s = f1 + f2;
    int e0 = -1, e1 = -1; float w0 = 0.f, w1 = 0.f;
    if (s > 0.0) {
        if (f1 > 0.0) { e0 = i1; w0 = (float)(f1 / s); }
        if (f2 > 0.0) { e1 = i2; w1 = (float)(f2 / s); }
    }
    toke[i * 2 + 0] = e0; toke[i * 2 + 1] = e1;
    tokw[i * 2 + 0] = w0; tokw[i * 2 + 1] = w1;
    if (e0 >= 0) atomicAdd(&cnt[e0], 1);
    if (e1 >= 0) atomicAdd(&cnt[e1], 1);
}

__global__ void offs_k(const int* __restrict__ cnt, int* __restrict__ offs)
{
    if (threadIdx.x == 0) {
        int a = 0;
        for (int e = 0; e < NE; ++e) { offs[e] = a; a += cnt[e]; }
    }
}

__global__ __launch_bounds__(256) void assign_k(const int* __restrict__ toke,
    const int* __restrict__ offs, int* __restrict__ cur,
    int* __restrict__ toklist, int* __restrict__ tokslot)
{
    const int i = blockIdx.x * 256 + threadIdx.x;
    if (i >= NTOK) return;
    #pragma unroll
    for (int j = 0; j < 2; ++j) {
        int e = toke[i * 2 + j];
        if (e >= 0) {
            int p = atomicAdd(&cur[e], 1);
            int sl = offs[e] + p;
            toklist[sl] = i;
            tokslot[i * 2 + j] = sl;
        } else {
            tokslot[i * 2 + j] = -1;
        }
    }
}

__global__ __launch_bounds__(256) void combine_k(float* __restrict__ out,
    const f16* __restrict__ Yg, const int* __restrict__ tokslot, const float* __restrict__ tokw)
{
    const int i = blockIdx.x;
    int s0 = tokslot[i * 2 + 0], s1 = tokslot[i * 2 + 1];
    float w0 = (s0 >= 0) ? tokw[i * 2 + 0] : 0.f;
    float w1 = (s1 >= 0) ? tokw[i * 2 + 1] : 0.f;
    const f16x4* y0 = (const f16x4*)(Yg + (size_t)(s0 < 0 ? 0 : s0) * DOUT);
    const f16x4* y1 = (const f16x4*)(Yg + (size_t)(s1 < 0 ? 0 : s1) * DOUT);
    float4* o = (float4*)(out + (size_t)i * DOUT);
    for (int c = threadIdx.x; c < DOUT / 4; c += 256) {
        float4 v = o[c];
        f16x4 a = y0[c], b = y1[c];
        v.x += w0 * (float)a[0] + w1 * (float)b[0];
        v.y += w0 * (float)a[1] + w1 * (float)b[1];
        v.z += w0 * (float)a[2] + w1 * (float)b[2];
        v.w += w0 * (float)a[3] + w1 * (float)b[3];
        o[c] = v;
    }
}

// ---------------------------------------------------------------------------
extern "C" void kernel_launch(void* const* d_in, const int* in_sizes, int n_in,
                              void* d_out, int out_size, void* d_ws, size_t ws_size,
                              hipStream_t stream)
{
    const float* X  = (const float*)d_in[0];
    const float* GW = (const float*)d_in[1];
    const float* Wp = (const float*)d_in[2];
    const float* bp = (const float*)d_in[3];
    const float* We = (const float*)d_in[4];
    const float* be = (const float*)d_in[5];
    float* out = (float*)d_out;

    char* ws = (char*)d_ws;
    size_t o = 0;
    auto alloc = [&](size_t bytes) { char* p = ws + o; o += (bytes + 255) & ~(size_t)255; return p; };

    f16* Xhi = (f16*)alloc((size_t)NTOK * DIN * 2);
    const size_t aliasOff = o;                      // Yg aliases [Xlo..Tlo] (all dead by expert GEMM)
    f16* Xlo  = (f16*)alloc((size_t)NTOK * DIN * 2);
    f16* GThi = (f16*)alloc((size_t)NE * RNK * DIN * 2);
    f16* GTlo = (f16*)alloc((size_t)NE * RNK * DIN * 2);
    f16* Thi  = (f16*)alloc((size_t)NTOK * DIN * 2);
    f16* Tlo  = (f16*)alloc((size_t)NTOK * DIN * 2);
    f16* Yg = (f16*)(ws + aliasOff);                // 2*NTOK x DOUT f16 = 134 MB (fits alias span)
    f16* Wp16 = (f16*)alloc((size_t)DOUT * DIN * 2);
    f16* We16 = (f16*)alloc((size_t)NE * DOUT * DIN * 2);
    f16* Ghi  = (f16*)alloc((size_t)NE * RNK * RNK * 2);
    f16* Glo  = (f16*)alloc((size_t)NE * RNK * RNK * 2);
    double* normx = (double*)alloc((size_t)NTOK * 8);
    float* rowpT  = (float*)alloc((size_t)NTOK * 64 * 4);
    float* rowpU  = (float*)alloc((size_t)NTOK * 64 * 4);
    float* tokw   = (float*)alloc((size_t)NTOK * 2 * 4);
    int* toke     = (int*)alloc((size_t)NTOK * 2 * 4);
    int* tokslot  = (int*)alloc((size_t)NTOK * 2 * 4);
    int* toklist  = (int*)alloc((size_t)2 * NTOK * 4);
    int* cnt      = (int*)alloc(64 * 4);
    int* offs = cnt + 8;
    int* cur  = cnt + 16;

    if (ws_size < o) return; // ws too small -> output stays zero (visible failure)

    hipMemsetAsync(cnt, 0, 64 * 4, stream);

    split_x_k<<<NTOK, 256, 0, stream>>>(X, Xhi, Xlo, normx);
    trans_gate_k<<<dim3(RNK / 64, DIN / 64, NE), 256, 0, stream>>>(GW, GThi, GTlo);
    conv16_k<<<2048, 256, 0, stream>>>(Wp, Wp16, (long)DOUT * DIN / 4);
    conv16_k<<<4096, 256, 0, stream>>>(We, We16, (long)NE * DOUT * DIN / 4);

    // G = V^T V (split precision)
    gemm_k<0><<<dim3(4, 4, NE), 256, 0, stream>>>(GThi, GTlo, GThi, GTlo,
        Ghi, Glo, nullptr, nullptr, nullptr);
    // T = X V (split) + ||t||^2 partials  (1-D XCD-swizzled grid)
    gemm_k<1><<<2048, 256, 0, stream>>>(Xhi, Xlo, GThi, GTlo,
        Thi, Tlo, rowpT, nullptr, nullptr);
    // s2 = t G t^T partials (split)
    gemm_k<2><<<dim3(64, 4, NE), 256, 0, stream>>>(Thi, Tlo, Ghi, Glo,
        nullptr, nullptr, rowpU, Thi, Tlo);

    route_k<<<NTOK / 256, 256, 0, stream>>>(normx, rowpT, rowpU, cnt, toke, tokw);
    offs_k<<<1, 1, 0, stream>>>(cnt, offs);
    assign_k<<<NTOK / 256, 256, 0, stream>>>(toke, offs, cur, toklist, tokslot);

    // pretrained: out = X Wp^T + bp   (256^2 tile, XCD-swizzled, ring-4)
    gemm256_k<3><<<32 * 16, 512, 0, stream>>>(Xhi, Wp16,
        out, nullptr, bp, nullptr, nullptr, nullptr, 32, 16);
    // experts (gathered rows): Yg[slot] = f16(X[tok] We^T + be)
    gemm256_k<4><<<NE * 32 * 16, 512, 0, stream>>>(Xhi, We16,
        nullptr, Yg, be, toklist, cnt, offs, 32, 16);

    combine_k<<<NTOK, 256, 0, stream>>>(out, Yg, tokslot, tokw);
}

// Round 8
// 2499.448 us; speedup vs baseline: 1.1254x; 1.0636x over previous
//
#include <hip/hip_runtime.h>

typedef _Float16 f16;
typedef _Float16 f16x4 __attribute__((ext_vector_type(4)));
typedef _Float16 f16x8 __attribute__((ext_vector_type(8)));
typedef float    f32x4 __attribute__((ext_vector_type(4)));

static constexpr int NTOK = 8192;
static constexpr int DIN  = 4096;
static constexpr int DOUT = 4096;
static constexpr int NE   = 8;
static constexpr int RNK  = 512;
static constexpr float LOSC  = 2048.0f;   // lo terms stored pre-scaled by 2^11 (fp16 denormal dodge)
static constexpr float ILOSC = 1.0f/2048.0f;

#define AS1 __attribute__((address_space(1)))
#define AS3 __attribute__((address_space(3)))

// ---------------------------------------------------------------------------
// split hidden_states into fp16 hi/lo and compute ||x||^2 per row (double)
// ---------------------------------------------------------------------------
__global__ __launch_bounds__(256) void split_x_k(const float* __restrict__ X,
    f16* __restrict__ Xhi, f16* __restrict__ Xlo, double* __restrict__ normx)
{
    const int row = blockIdx.x, tid = threadIdx.x;
    const float4* xr = (const float4*)(X + (size_t)row * DIN);
    f16x4* hr = (f16x4*)(Xhi + (size_t)row * DIN);
    f16x4* lr = (f16x4*)(Xlo + (size_t)row * DIN);
    double acc = 0.0;
    #pragma unroll
    for (int it = 0; it < 4; ++it) {
        int i = tid + it * 256;
        float4 v = xr[i];
        float vv[4] = {v.x, v.y, v.z, v.w};
        f16x4 h, l;
        #pragma unroll
        for (int j = 0; j < 4; ++j) {
            f16 hh = (f16)vv[j];
            h[j] = hh;
            l[j] = (f16)((vv[j] - (float)hh) * LOSC);
            acc += (double)vv[j] * (double)vv[j];
        }
        hr[i] = h; lr[i] = l;
    }
    #pragma unroll
    for (int m = 1; m < 64; m <<= 1) acc += __shfl_xor(acc, m, 64);
    __shared__ double sred[4];
    if ((tid & 63) == 0) sred[tid >> 6] = acc;
    __syncthreads();
    if (tid == 0) normx[row] = sred[0] + sred[1] + sred[2] + sred[3];
}

// ---------------------------------------------------------------------------
// transpose gate_weight [E][D][R] fp32 -> GT [E][R][D] fp16 hi/lo (row-major, K contiguous)
// ---------------------------------------------------------------------------
__global__ __launch_bounds__(256) void trans_gate_k(const float* __restrict__ GW,
    f16* __restrict__ GThi, f16* __restrict__ GTlo)
{
    __shared__ float t[64][65];
    const int e = blockIdx.z;
    const int r0 = blockIdx.x * 64, d0 = blockIdx.y * 64;
    const float* src = GW + (size_t)e * DIN * RNK;
    const int c = threadIdx.x & 63, rq = threadIdx.x >> 6;
    #pragma unroll
    for (int i = 0; i < 16; ++i) {
        int dr = i * 4 + rq;
        t[dr][c] = src[(size_t)(d0 + dr) * RNK + r0 + c];
    }
    __syncthreads();
    const size_t obase = (size_t)e * RNK * DIN;
    #pragma unroll
    for (int i = 0; i < 16; ++i) {
        int rr = i * 4 + rq;
        float v = t[c][rr];
        f16 h = (f16)v;
        size_t idx = obase + (size_t)(r0 + rr) * DIN + d0 + c;
        GThi[idx] = h;
        GTlo[idx] = (f16)((v - (float)h) * LOSC);
    }
}

// ---------------------------------------------------------------------------
// fp32 -> fp16 elementwise convert (weights; single precision level is enough)
// ---------------------------------------------------------------------------
__global__ __launch_bounds__(256) void conv16_k(const float* __restrict__ src,
    f16* __restrict__ dst, long n4)
{
    long i = (long)blockIdx.x * 256 + threadIdx.x;
    const long stride = (long)gridDim.x * 256;
    for (; i < n4; i += stride) {
        float4 v = ((const float4*)src)[i];
        f16x4 h = { (f16)v.x, (f16)v.y, (f16)v.z, (f16)v.w };
        ((f16x4*)dst)[i] = h;
    }
}

// ---------------------------------------------------------------------------
// Split-precision 128x128x(BK=64) MFMA GEMM, 2-phase dbuf (r4 shape), 512 thr
// = 8 waves (2M x 4N, wave tile 64x32) -> acc 64 f32/wave -> 2 waves/SIMD.
// Granule swizzle: stage col (u^(r&7))*8, read (kby ^ ((row&7)<<4)) — 0 conflicts.
// KIND 0: G = V^T V      (M=N=512, K=4096, z=expert) -> Ghi/Glo
// KIND 1: T = X Vt^T     (M=8192, N=4096, K=4096) -> Thi/Tlo + rowpT[128]; XCD swizzle
// KIND 2: s2 = sum((TG) o T) (M=8192, N=512/e, K=512, z=expert) -> rowpU[128]
// ---------------------------------------------------------------------------
template<int KIND>
__global__ __launch_bounds__(512, 1) void gemm_k(
    const f16* __restrict__ Ah, const f16* __restrict__ Al,
    const f16* __restrict__ Bh, const f16* __restrict__ Bl,
    f16* __restrict__ Chi, f16* __restrict__ Clo,
    float* __restrict__ rowp,
    const f16* __restrict__ Th, const f16* __restrict__ Tl)
{
    constexpr int KDIM = (KIND == 2) ? 512 : 4096;
    constexpr int LDB  = (KIND == 2) ? 512 : 4096;

    int bm, bn, z;
    if constexpr (KIND == 1) {
        // bijective XCD swizzle: 2048 blocks, 8 XCDs, 256/chunk; bm-innermost
        const int orig = blockIdx.x;
        const int wg = (orig & 7) * 256 + (orig >> 3);
        bm = wg & 63; bn = wg >> 6; z = 0;
    } else {
        bm = blockIdx.x; bn = blockIdx.y; z = blockIdx.z;
    }
    const int tid = threadIdx.x;
    const int lane = tid & 63, wv = tid >> 6;
    const int wr = wv >> 2, wc = wv & 3;          // 2 x 4 wave grid; wave tile 64x32
    const int m0 = bm * 128, n0 = bn * 128;

    __shared__ f16 smem[65536]; // 2 bufs x [Ah 8192|Bh 8192|Al 8192|Bl 8192] f16

    long aBase = 0, bBase = 0;
    if constexpr (KIND == 0) { aBase = (long)z * RNK * DIN; bBase = aBase; }
    if constexpr (KIND == 2) { aBase = (long)z * RNK; bBase = (long)z * RNK * RNK; }

    // per-thread staging sources (pre-swizzled granule): g=j*512+tid, r=g>>3, u=g&7
    long s2A[2], s2B[2];
    #pragma unroll
    for (int j = 0; j < 2; ++j) {
        int g = j * 512 + tid;
        int r = g >> 3, u = g & 7;
        int sc = (u ^ (r & 7)) * 8;   // granule swizzle (f16 elems)
        s2A[j] = aBase + (long)(m0 + r) * DIN + sc;
        s2B[j] = bBase + (long)(n0 + r) * LDB + sc;
    }

    auto stage4 = [&](int buf, int kOff) {
        const int e0 = buf * 32768;
        #pragma unroll
        for (int j = 0; j < 2; ++j) {
            int g = j * 512 + tid;
            __builtin_amdgcn_global_load_lds((const AS1 void*)(Ah + s2A[j] + kOff),
                (AS3 void*)(&smem[e0 + g * 8]), 16, 0, 0);
            __builtin_amdgcn_global_load_lds((const AS1 void*)(Bh + s2B[j] + kOff),
                (AS3 void*)(&smem[e0 + 8192 + g * 8]), 16, 0, 0);
            __builtin_amdgcn_global_load_lds((const AS1 void*)(Al + s2A[j] + kOff),
                (AS3 void*)(&smem[e0 + 16384 + g * 8]), 16, 0, 0);
            __builtin_amdgcn_global_load_lds((const AS1 void*)(Bl + s2B[j] + kOff),
                (AS3 void*)(&smem[e0 + 24576 + g * 8]), 16, 0, 0);
        }
    };

    f32x4 acc[4][2], accB_[4][2];
    #pragma unroll
    for (int a = 0; a < 4; ++a)
        #pragma unroll
        for (int b = 0; b < 2; ++b) {
            acc[a][b]   = f32x4{0.f, 0.f, 0.f, 0.f};
            accB_[a][b] = f32x4{0.f, 0.f, 0.f, 0.f};
        }

    const int li = lane & 15;

    stage4(0, 0);
    __syncthreads();

    int cur = 0;
    for (int k0 = 0; k0 < KDIM; k0 += 64) {
        if (k0 + 64 < KDIM) stage4(cur ^ 1, k0 + 64);   // next tile flies under compute
        const char* sm = (const char*)smem + cur * 65536;
        #pragma unroll
        for (int kk = 0; kk < 64; kk += 32) {
            const int kby = (kk + ((lane >> 4) << 3)) << 1; // logical byte col of lane's 8 elems
            f16x8 bhf[2], blf[2];
            #pragma unroll
            for (int fn = 0; fn < 2; ++fn) {
                int rb = wc * 32 + fn * 16 + li;
                int off = rb * 128 + (kby ^ ((rb & 7) << 4));
                bhf[fn] = *(const f16x8*)(sm + 16384 + off);
                blf[fn] = *(const f16x8*)(sm + 49152 + off);
            }
            #pragma unroll
            for (int fm = 0; fm < 4; ++fm) {
                int ra = wr * 64 + fm * 16 + li;
                int offA = ra * 128 + (kby ^ ((ra & 7) << 4));
                f16x8 ahf = *(const f16x8*)(sm + offA);
                f16x8 alv = *(const f16x8*)(sm + 32768 + offA);
                #pragma unroll
                for (int fn = 0; fn < 2; ++fn) {
                    acc[fm][fn]   = __builtin_amdgcn_mfma_f32_16x16x32_f16(ahf, bhf[fn], acc[fm][fn],   0, 0, 0);
                    accB_[fm][fn] = __builtin_amdgcn_mfma_f32_16x16x32_f16(ahf, blf[fn], accB_[fm][fn], 0, 0, 0);
                    accB_[fm][fn] = __builtin_amdgcn_mfma_f32_16x16x32_f16(alv, bhf[fn], accB_[fm][fn], 0, 0, 0);
                }
            }
        }
        __syncthreads();
        cur ^= 1;
    }

    const int lr_ = (lane >> 4) * 4;
    const int lc_ = lane & 15;
    const int rB = m0 + wr * 64;
    const int cB = n0 + wc * 32;

    if constexpr (KIND == 0) {
        #pragma unroll
        for (int fm = 0; fm < 4; ++fm)
            #pragma unroll
            for (int fn = 0; fn < 2; ++fn)
                #pragma unroll
                for (int j = 0; j < 4; ++j) {
                    float v = acc[fm][fn][j] + accB_[fm][fn][j] * ILOSC;
                    long row = rB + fm * 16 + lr_ + j;
                    long col = cB + fn * 16 + lc_;
                    long idx = (long)z * RNK * RNK + row * RNK + col;
                    f16 h = (f16)v;
                    Chi[idx] = h;
                    Clo[idx] = (f16)((v - (float)h) * LOSC);
                }
    } else {
        // 32-col slot index (128 slots across 4096 cols)
        const int slot = (KIND == 1) ? (bn * 4 + wc) : (z * 16 + bn * 4 + wc);
        #pragma unroll
        for (int fm = 0; fm < 4; ++fm) {
            float rs[4] = {0.f, 0.f, 0.f, 0.f};
            #pragma unroll
            for (int fn = 0; fn < 2; ++fn)
                #pragma unroll
                for (int j = 0; j < 4; ++j) {
                    float v = acc[fm][fn][j] + accB_[fm][fn][j] * ILOSC;
                    long row = rB + fm * 16 + lr_ + j;
                    long col = cB + fn * 16 + lc_;
                    if constexpr (KIND == 1) {
                        long idx = row * (long)DIN + col;
                        f16 h = (f16)v;
                        Chi[idx] = h;
                        Clo[idx] = (f16)((v - (float)h) * LOSC);
                        rs[j] += v * v;
                    } else {
                        long tidx = row * (long)DIN + (long)z * RNK + col;
                        float tv = (float)Th[tidx] + (float)Tl[tidx] * ILOSC;
                        rs[j] += v * tv;
                    }
                }
            #pragma unroll
            for (int j = 0; j < 4; ++j) {
                float s = rs[j];
                s += __shfl_xor(s, 1, 64);
                s += __shfl_xor(s, 2, 64);
                s += __shfl_xor(s, 4, 64);
                s += __shfl_xor(s, 8, 64);
                if (lc_ == 0) {
                    long row = rB + fm * 16 + lr_ + j;
                    rowp[row * 128 + slot] = s;
                }
            }
        }
    }
}

// ---------------------------------------------------------------------------
// 256x256x(BK=64) DOUBLE-BUFFERED MFMA GEMM (r4 exact), 512 threads (2M x 4N),
// XCD-bijective-swizzled 1D grid, bm-innermost decode, granule-swizzled LDS.
// KIND 3: pretrained dense  -> fp32 out + bias[n]
// KIND 4: expert gather     -> f16 Yg rows via toklist, z = expert, bias[z][n]
// ---------------------------------------------------------------------------
template<int KIND>
__global__ __launch_bounds__(512, 1) void gemm256_k(
    const f16* __restrict__ A, const f16* __restrict__ Bm,
    float* __restrict__ Cf, f16* __restrict__ Ch, const float* __restrict__ bias,
    const int* __restrict__ toklist, const int* __restrict__ cnt, const int* __restrict__ offs,
    int Mtiles, int Ntiles)
{
    // bijective XCD swizzle (m204): each XCD gets a contiguous logical range
    const int nwg = gridDim.x;
    const int orig = blockIdx.x;
    const int q = nwg >> 3, rr8 = nwg & 7;
    const int xcd = orig & 7, pos = orig >> 3;
    const int wg = (xcd < rr8 ? xcd * (q + 1) : rr8 * (q + 1) + (xcd - rr8) * q) + pos;
    const int bm = wg % Mtiles;
    const int rest = wg / Mtiles;
    const int bn = rest % Ntiles;
    const int z  = rest / Ntiles;

    const int tid = threadIdx.x;
    const int lane = tid & 63, wv = tid >> 6;
    const int wr = wv >> 2, wc = wv & 3;          // 2 x 4 wave grid
    const int m0 = bm * 256, n0 = bn * 256;

    int cntz = 0, offz = 0;
    if constexpr (KIND == 4) {
        cntz = cnt[z]; offz = offs[z];
        if (m0 >= cntz) return;
    }

    __shared__ f16 smem[65536];                   // 2 x (A[16384] B[16384]) f16

    long bBase = 0;
    if constexpr (KIND == 4) bBase = (long)z * DOUT * DIN;

    // per-thread staging sources: 4 A-chunks + 4 B-chunks of 16B per K-step
    long srcA[4], srcB[4];
    #pragma unroll
    for (int i = 0; i < 4; ++i) {
        int g = i * 512 + tid;                    // [0, 2048)
        int r = g >> 3, u = g & 7;
        int sc = (u ^ (r & 7)) * 8;               // pre-swizzled logical col (f16 elems)
        if constexpr (KIND == 4) {
            int rg = m0 + r;
            int tok = (rg < cntz) ? toklist[offz + rg] : 0;
            srcA[i] = (long)tok * DIN + sc;
        } else {
            srcA[i] = (long)(m0 + r) * DIN + sc;
        }
        srcB[i] = bBase + (long)(n0 + r) * DIN + sc;
    }

    auto stage = [&](int buf, int k0) {
        const int e0 = buf * 32768;
        #pragma unroll
        for (int i = 0; i < 4; ++i) {
            int g = i * 512 + tid;
            __builtin_amdgcn_global_load_lds(
                (const AS1 void*)(A + srcA[i] + k0),
                (AS3 void*)(&smem[e0 + g * 8]), 16, 0, 0);
        }
        #pragma unroll
        for (int i = 0; i < 4; ++i) {
            int g = i * 512 + tid;
            __builtin_amdgcn_global_load_lds(
                (const AS1 void*)(Bm + srcB[i] + k0),
                (AS3 void*)(&smem[e0 + 16384 + g * 8]), 16, 0, 0);
        }
    };

    f32x4 acc[8][4];
    #pragma unroll
    for (int a = 0; a < 8; ++a)
        #pragma unroll
        for (int b = 0; b < 4; ++b) acc[a][b] = f32x4{0.f, 0.f, 0.f, 0.f};

    stage(0, 0);
    __syncthreads();

    int cur = 0;
    for (int k0 = 0; k0 < DIN; k0 += 64) {
        if (k0 + 64 < DIN) stage(cur ^ 1, k0 + 64);   // next tile flies under compute
        const char* sm = (const char*)smem + cur * 65536;
        #pragma unroll
        for (int kk = 0; kk < 64; kk += 32) {
            const int kby = (kk + ((lane >> 4) << 3)) << 1;
            f16x8 bhf[4];
            #pragma unroll
            for (int f = 0; f < 4; ++f) {
                int rb = wc * 64 + f * 16 + (lane & 15);
                bhf[f] = *(const f16x8*)(sm + 32768 + rb * 128 + (kby ^ ((rb & 7) << 4)));
            }
            #pragma unroll
            for (int fm = 0; fm < 8; ++fm) {
                int ra = wr * 128 + fm * 16 + (lane & 15);
                f16x8 ahf = *(const f16x8*)(sm + ra * 128 + (kby ^ ((ra & 7) << 4)));
                #pragma unroll
                for (int fn = 0; fn < 4; ++fn)
                    acc[fm][fn] = __builtin_amdgcn_mfma_f32_16x16x32_f16(ahf, bhf[fn], acc[fm][fn], 0, 0, 0);
            }
        }
        __syncthreads();
        cur ^= 1;
    }

    const int lr_ = (lane >> 4) * 4;
    const int lc_ = lane & 15;
    #pragma unroll
    for (int fm = 0; fm < 8; ++fm)
        #pragma unroll
        for (int fn = 0; fn < 4; ++fn)
            #pragma unroll
            for (int j = 0; j < 4; ++j) {
                int rloc = wr * 128 + fm * 16 + lr_ + j;
                long col = n0 + wc * 64 + fn * 16 + lc_;
                if constexpr (KIND == 4) {
                    if (m0 + rloc < cntz) {
                        long row = (long)offz + m0 + rloc;
                        Ch[row * (long)DOUT + col] = (f16)(acc[fm][fn][j] + bias[(long)z * DOUT + col]);
                    }
                } else {
                    long row = m0 + rloc;
                    Cf[row * (long)DOUT + col] = acc[fm][fn][j] + bias[col];
                }
            }
}

// ---------------------------------------------------------------------------
// routing: residual^2 = ||x||^2 - 2||t||^2 + tGt ; softmax(-r) ; top-2 & >1/8 mask
// rowp layout: 128 slots of 32 cols; expert e owns slots [e*16, e*16+16)
// ---------------------------------------------------------------------------
__global__ __launch_bounds__(256) void route_k(const double* __restrict__ normx,
    const float* __restrict__ rowpT, const float* __restrict__ rowpU,
    int* __restrict__ cnt, int* __restrict__ toke, float* __restrict__ tokw)
{
    const int i = blockIdx.x * 256 + threadIdx.x;
    if (i >= NTOK) return;
    const double nx = normx[i];
    double r[NE];
    #pragma unroll
    for (int e = 0; e < NE; ++e) {
        double tn = 0.0, s2 = 0.0;
        #pragma unroll
        for (int s = 0; s < 16; ++s) {
            tn += (double)rowpT[(long)i * 128 + e * 16 + s];
            s2 += (double)rowpU[(long)i * 128 + e * 16 + s];
        }
        double r2 = nx - 2.0 * tn + s2;
        r[e] = sqrt(r2 > 0.0 ? r2 : 0.0);
    }
    double rmin = r[0];
    #pragma unroll
    for (int e = 1; e < NE; ++e) if (r[e] < rmin) rmin = r[e];
    double w[NE], S = 0.0;
    #pragma unroll
    for (int e = 0; e < NE; ++e) { w[e] = exp(rmin - r[e]); S += w[e]; }
    double rw[NE];
    #pragma unroll
    for (int e = 0; e < NE; ++e) rw[e] = w[e] / S;
    // top-2, first-occurrence tie-break (matches lax.top_k)
    int i1 = 0;
    #pragma unroll
    for (int e = 1; e < NE; ++e) if (rw[e] > rw[i1]) i1 = e;
    int i2 = (i1 == 0) ? 1 : 0;
    #pragma unroll
    for (int e = 0; e < NE; ++e) if (e != i2 && e != i1 && rw[e] > rw[i2]) i2 = e;
    double f1 = (rw[i1] > 0.125) ? rw[i1] : 0.0;
    double f2 = (rw[i2] > 0.125) ? rw[i2] : 0.0;
    double s = f1 + f2;
    int e0 = -1, e1 = -1; float w0 = 0.f, w1 = 0.f;
    if (s > 0.0) {
        if (f1 > 0.0) { e0 = i1; w0 = (float)(f1 / s); }
        if (f2 > 0.0) { e1 = i2; w1 = (float)(f2 / s); }
    }
    toke[i * 2 + 0] = e0; toke[i * 2 + 1] = e1;
    tokw[i * 2 + 0] = w0; tokw[i * 2 + 1] = w1;
    if (e0 >= 0) atomicAdd(&cnt[e0], 1);
    if (e1 >= 0) atomicAdd(&cnt[e1], 1);
}

__global__ void offs_k(const int* __restrict__ cnt, int* __restrict__ offs)
{
    if (threadIdx.x == 0) {
        int a = 0;
        for (int e = 0; e < NE; ++e) { offs[e] = a; a += cnt[e]; }
    }
}

__global__ __launch_bounds__(256) void assign_k(const int* __restrict__ toke,
    const int* __restrict__ offs, int* __restrict__ cur,
    int* __restrict__ toklist, int* __restrict__ tokslot)
{
    const int i = blockIdx.x * 256 + threadIdx.x;
    if (i >= NTOK) return;
    #pragma unroll
    for (int j = 0; j < 2; ++j) {
        int e = toke[i * 2 + j];
        if (e >= 0) {
            int p = atomicAdd(&cur[e], 1);
            int sl = offs[e] + p;
            toklist[sl] = i;
            tokslot[i * 2 + j] = sl;
        } else {
            tokslot[i * 2 + j] = -1;
        }
    }
}

__global__ __launch_bounds__(256) void combine_k(float* __restrict__ out,
    const f16* __restrict__ Yg, const int* __restrict__ tokslot, const float* __restrict__ tokw)
{
    const int i = blockIdx.x;
    int s0 = tokslot[i * 2 + 0], s1 = tokslot[i * 2 + 1];
    float w0 = (s0 >= 0) ? tokw[i * 2 + 0] : 0.f;
    float w1 = (s1 >= 0) ? tokw[i * 2 + 1] : 0.f;
    const f16x4* y0 = (const f16x4*)(Yg + (size_t)(s0 < 0 ? 0 : s0) * DOUT);
    const f16x4* y1 = (const f16x4*)(Yg + (size_t)(s1 < 0 ? 0 : s1) * DOUT);
    float4* o = (float4*)(out + (size_t)i * DOUT);
    for (int c = threadIdx.x; c < DOUT / 4; c += 256) {
        float4 v = o[c];
        f16x4 a = y0[c], b = y1[c];
        v.x += w0 * (float)a[0] + w1 * (float)b[0];
        v.y += w0 * (float)a[1] + w1 * (float)b[1];
        v.z += w0 * (float)a[2] + w1 * (float)b[2];
        v.w += w0 * (float)a[3] + w1 * (float)b[3];
        o[c] = v;
    }
}

// ---------------------------------------------------------------------------
extern "C" void kernel_launch(void* const* d_in, const int* in_sizes, int n_in,
                              void* d_out, int out_size, void* d_ws, size_t ws_size,
                              hipStream_t stream)
{
    const float* X  = (const float*)d_in[0];
    const float* GW = (const float*)d_in[1];
    const float* Wp = (const float*)d_in[2];
    const float* bp = (const float*)d_in[3];
    const float* We = (const float*)d_in[4];
    const float* be = (const float*)d_in[5];
    float* out = (float*)d_out;

    char* ws = (char*)d_ws;
    size_t o = 0;
    auto alloc = [&](size_t bytes) { char* p = ws + o; o += (bytes + 255) & ~(size_t)255; return p; };

    f16* Xhi = (f16*)alloc((size_t)NTOK * DIN * 2);
    const size_t aliasOff = o;                      // Yg aliases [Xlo..Tlo] (all dead by expert GEMM)
    f16* Xlo  = (f16*)alloc((size_t)NTOK * DIN * 2);
    f16* GThi = (f16*)alloc((size_t)NE * RNK * DIN * 2);
    f16* GTlo = (f16*)alloc((size_t)NE * RNK * DIN * 2);
    f16* Thi  = (f16*)alloc((size_t)NTOK * DIN * 2);
    f16* Tlo  = (f16*)alloc((size_t)NTOK * DIN * 2);
    f16* Yg = (f16*)(ws + aliasOff);                // 2*NTOK x DOUT f16 = 134 MB (fits alias span)
    f16* Wp16 = (f16*)alloc((size_t)DOUT * DIN * 2);
    f16* We16 = (f16*)alloc((size_t)NE * DOUT * DIN * 2);
    f16* Ghi  = (f16*)alloc((size_t)NE * RNK * RNK * 2);
    f16* Glo  = (f16*)alloc((size_t)NE * RNK * RNK * 2);
    double* normx = (double*)alloc((size_t)NTOK * 8);
    float* rowpT  = (float*)alloc((size_t)NTOK * 128 * 4);
    float* rowpU  = (float*)alloc((size_t)NTOK * 128 * 4);
    float* tokw   = (float*)alloc((size_t)NTOK * 2 * 4);
    int* toke     = (int*)alloc((size_t)NTOK * 2 * 4);
    int* tokslot  = (int*)alloc((size_t)NTOK * 2 * 4);
    int* toklist  = (int*)alloc((size_t)2 * NTOK * 4);
    int* cnt      = (int*)alloc(64 * 4);
    int* offs = cnt + 8;
    int* cur  = cnt + 16;

    if (ws_size < o) return; // ws too small -> output stays zero (visible failure)

    hipMemsetAsync(cnt, 0, 64 * 4, stream);

    split_x_k<<<NTOK, 256, 0, stream>>>(X, Xhi, Xlo, normx);
    trans_gate_k<<<dim3(RNK / 64, DIN / 64, NE), 256, 0, stream>>>(GW, GThi, GTlo);
    conv16_k<<<2048, 256, 0, stream>>>(Wp, Wp16, (long)DOUT * DIN / 4);
    conv16_k<<<4096, 256, 0, stream>>>(We, We16, (long)NE * DOUT * DIN / 4);

    // G = V^T V (split precision)
    gemm_k<0><<<dim3(4, 4, NE), 512, 0, stream>>>(GThi, GTlo, GThi, GTlo,
        Ghi, Glo, nullptr, nullptr, nullptr);
    // T = X V (split) + ||t||^2 partials  (1-D XCD-swizzled grid)
    gemm_k<1><<<2048, 512, 0, stream>>>(Xhi, Xlo, GThi, GTlo,
        Thi, Tlo, rowpT, nullptr, nullptr);
    // s2 = t G t^T partials (split)
    gemm_k<2><<<dim3(64, 4, NE), 512, 0, stream>>>(Thi, Tlo, Ghi, Glo,
        nullptr, nullptr, rowpU, Thi, Tlo);

    route_k<<<NTOK / 256, 256, 0, stream>>>(normx, rowpT, rowpU, cnt, toke, tokw);
    offs_k<<<1, 1, 0, stream>>>(cnt, offs);
    assign_k<<<NTOK / 256, 256, 0, stream>>>(toke, offs, cur, toklist, tokslot);

    // pretrained: out = X Wp^T + bp   (256^2 tile, XCD-swizzled, dbuf)
    gemm256_k<3><<<32 * 16, 512, 0, stream>>>(Xhi, Wp16,
        out, nullptr, bp, nullptr, nullptr, nullptr, 32, 16);
    // experts (gathered rows): Yg[slot] = f16(X[tok] We^T + be)
    gemm256_k<4><<<NE * 32 * 16, 512, 0, stream>>>(Xhi, We16,
        nullptr, Yg, be, toklist, cnt, offs, 32, 16);

    combine_k<<<NTOK, 256, 0, stream>>>(out, Yg, tokslot, tokw);
}